// Round 10
// baseline (444.452 us; speedup 1.0000x reference)
//
#include <hip/hip_runtime.h>
#include <math.h>

#define BN_K 0.9999950000374997f  // 1/sqrt(1+1e-5)

static __device__ __forceinline__ float lrelu02(float x) { return x > 0.f ? x : 0.2f * x; }

typedef _Float16 half8 __attribute__((ext_vector_type(8)));
typedef __fp16 fp16x2 __attribute__((ext_vector_type(2)));
typedef float f32x4 __attribute__((ext_vector_type(4)));

static __device__ __forceinline__ unsigned short f2h(float x)
{
    union { _Float16 h; unsigned short u; } q;
    q.h = (_Float16)x;
    return q.u;
}
static __device__ __forceinline__ float h2f(unsigned short u)
{
    union { unsigned short u; _Float16 h; } q;
    q.u = u;
    return (float)q.h;
}
static __device__ __forceinline__ unsigned pkrtz(float a, float b)
{
    union { fp16x2 h; unsigned u; } q;
    q.h = __builtin_amdgcn_cvt_pkrtz(a, b);
    return q.u;
}

// ---- tiny precompute: v0, v1 attention-edge vectors; b2p = edb2 + edbb @ edW2 ----
__global__ void k_ae_vec(const float* __restrict__ We0, const float* __restrict__ ae0,
                         const float* __restrict__ We1, const float* __restrict__ ae1,
                         const float* __restrict__ edbb, const float* __restrict__ edW2,
                         const float* __restrict__ edb2,
                         float* __restrict__ v0, float* __restrict__ v1,
                         float* __restrict__ b2p)
{
    int t = threadIdx.x;
    if (t < 64) {
        int h = t >> 4, k = t & 15;
        float s = 0.f;
        for (int c = 0; c < 64; ++c) s += We0[k * 256 + h * 64 + c] * ae0[h * 64 + c];
        v0[h * 16 + k] = s;
    } else if (t < 80) {
        int k = t - 64;
        float s = 0.f;
        for (int c = 0; c < 32; ++c) s += We1[k * 32 + c] * ae1[c];
        v1[k] = s;
    } else if (t < 144) {
        int n = t - 80;
        float s = 0.f;
        for (int k = 0; k < 128; ++k) s += edbb[k] * edW2[k * 64 + n];
        b2p[n] = edb2[n] + s;
    }
}

// ---------------- CSR build over dst (self-loops included: deg init = 1) ----------------
__global__ void k_deg_init(int* __restrict__ deg, int N)
{
    int i = blockIdx.x * blockDim.x + threadIdx.x;
    if (i < N) deg[i] = 1;
}

__global__ void k_deg_count(const int* __restrict__ dst, int* __restrict__ deg, int E)
{
    int e = blockIdx.x * blockDim.x + threadIdx.x;
    if (e < E) atomicAdd(&deg[dst[e]], 1);
}

#define SCHUNK 4096
__global__ __launch_bounds__(1024) void k_scan1(const int* __restrict__ deg,
                                                int* __restrict__ rowptr,
                                                int* __restrict__ bsum, int n)
{
    __shared__ int sbuf[1024];
    int b = blockIdx.x, t = threadIdx.x;
    int i0 = b * SCHUNK + t * 4;
    int v[4];
#pragma unroll
    for (int j = 0; j < 4; ++j) v[j] = (i0 + j < n) ? deg[i0 + j] : 0;
    int s = v[0] + v[1] + v[2] + v[3];
    sbuf[t] = s;
    __syncthreads();
    for (int d = 1; d < 1024; d <<= 1) {
        int tmp = (t >= d) ? sbuf[t - d] : 0;
        __syncthreads();
        sbuf[t] += tmp;
        __syncthreads();
    }
    int run = sbuf[t] - s;
#pragma unroll
    for (int j = 0; j < 4; ++j) {
        run += v[j];
        if (i0 + j < n) rowptr[i0 + j + 1] = run;  // chunk-local inclusive
    }
    if (t == 1023) bsum[b] = sbuf[1023];
    if (b == 0 && t == 0) rowptr[0] = 0;
}

__global__ void k_scan3(const int* __restrict__ bsum, const int* __restrict__ deg,
                        int* __restrict__ rowptr, int* __restrict__ cur, int n)
{
    int i = blockIdx.x * blockDim.x + threadIdx.x;
    if (i >= n) return;
    int chunk = i / SCHUNK;
    int off = 0;
    for (int b = 0; b < chunk; ++b) off += bsum[b];
    int r = rowptr[i + 1] + off;
    rowptr[i + 1] = r;
    cur[i] = r - deg[i];
}

__global__ void k_fill(const int* __restrict__ dst, int* __restrict__ cur,
                       int* __restrict__ col, int E, int N)
{
    int t = blockIdx.x * blockDim.x + threadIdx.x;
    if (t >= E + N) return;
    int d = (t < E) ? dst[t] : (t - E);
    int slot = atomicAdd(&cur[d], 1);
    col[slot] = t;  // eid: t<E original edge; t=E+i self-loop of node i
}

// ------- self-loop scatter-mean (from ea16) + fused self-loop attention-edge dots -------
__global__ __launch_bounds__(256) void k_loop_mean(
    const int* __restrict__ rowptr, const int* __restrict__ col,
    const unsigned short* __restrict__ ea16,
    const float* __restrict__ v0, const float* __restrict__ v1,
    float* __restrict__ a_e0, float* __restrict__ a_e1, int N, int E)
{
    int wv = threadIdx.x >> 6, lane = threadIdx.x & 63;
    int i = blockIdx.x * 4 + wv;
    if (i >= N) return;
    int beg = rowptr[i], end = rowptr[i + 1];
    int q = lane >> 4, k = lane & 15;
    float sum = 0.f;
    for (int p = beg + q; p < end; p += 4) {
        int eid = col[p];
        if (eid < E) sum += h2f(ea16[(size_t)eid * 16 + k]);
    }
    sum += __shfl_xor(sum, 16);
    sum += __shfl_xor(sum, 32);
    int cnt = end - beg - 1;  // exactly one self-loop per node
    float mean = sum / (float)max(cnt, 1);
    // dots: head q uses v0[q*16+k]; v1 computed by all, written by lane 0
    float p0 = mean * v0[q * 16 + k];
    float p1 = mean * v1[k];
#pragma unroll
    for (int mm = 1; mm < 16; mm <<= 1) { p0 += __shfl_xor(p0, mm); p1 += __shfl_xor(p1, mm); }
    if (k == 0) a_e0[(size_t)(E + i) * 4 + q] = p0;
    if (lane == 0) a_e1[E + i] = p1;
}

// ---------------- per-edge attention-edge terms + ea16 emit (original edges only) ------------
__global__ void k_edge_ae(const float* __restrict__ ea,
                          const float* __restrict__ v0, const float* __restrict__ v1,
                          float* __restrict__ a_e0, float* __restrict__ a_e1,
                          unsigned short* __restrict__ ea16, int E)
{
    int idx = blockIdx.x * blockDim.x + threadIdx.x;
    if (idx >= E) return;
    const float* row = ea + (size_t)idx * 16;
    float r[16];
#pragma unroll
    for (int k = 0; k < 16; ++k) r[k] = row[k];
#pragma unroll
    for (int h = 0; h < 4; ++h) {
        float s = 0.f;
#pragma unroll
        for (int k = 0; k < 16; ++k) s = fmaf(r[k], v0[h * 16 + k], s);
        a_e0[(size_t)idx * 4 + h] = s;
    }
    float s1 = 0.f;
#pragma unroll
    for (int k = 0; k < 16; ++k) s1 = fmaf(r[k], v1[k], s1);
    a_e1[idx] = s1;
#pragma unroll
    for (int k = 0; k < 16; k += 4) {
        ushort4 o;
        o.x = f2h(r[k]); o.y = f2h(r[k + 1]); o.z = f2h(r[k + 2]); o.w = f2h(r[k + 3]);
        *(ushort4*)(ea16 + (size_t)idx * 16 + k) = o;
    }
}

// ---------------- pack ALL weights into f16 MFMA fragments ----------------
// sigma(g,i)=8g+i; element (frag f, lane l, i) = W[k=32c+8g+i][n=16t+m], 0 if k>=K.
// frag ranges: [0,64) W0(128,256) c*16+t | [64,80) W1(256,32) c*2+t | [80,88) ndW1(32,128) t
// [88,104) ndW2(128,64) c*4+t | [104,120) ndW3(64,128) c*8+t
// [120,144) edW1(80,128) + bias row at k=80 | [144,160) edW2(128,64) rows scaled by g1*BN_K
__global__ __launch_bounds__(512) void k_pack_all(
    const float* __restrict__ W0, const float* __restrict__ W1,
    const float* __restrict__ nd1, const float* __restrict__ nd2, const float* __restrict__ nd3,
    const float* __restrict__ ed1, const float* __restrict__ ed2,
    const float* __restrict__ edb1, const float* __restrict__ edg,
    unsigned short* __restrict__ pw)
{
    int f = blockIdx.x, t = threadIdx.x;
    int l = t >> 3, i = t & 7, g = l >> 4, m = l & 15;
    float v;
    if (f < 64) {
        int q = f; int k = 32 * (q >> 4) + 8 * g + i, n = 16 * (q & 15) + m;
        v = W0[(size_t)k * 256 + n];
    } else if (f < 80) {
        int q = f - 64; int k = 32 * (q >> 1) + 8 * g + i, n = 16 * (q & 1) + m;
        v = W1[(size_t)k * 32 + n];
    } else if (f < 88) {
        int q = f - 80; int k = 8 * g + i, n = 16 * q + m;
        v = nd1[(size_t)k * 128 + n];
    } else if (f < 104) {
        int q = f - 88; int k = 32 * (q >> 2) + 8 * g + i, n = 16 * (q & 3) + m;
        v = nd2[(size_t)k * 64 + n];
    } else if (f < 120) {
        int q = f - 104; int k = 32 * (q >> 3) + 8 * g + i, n = 16 * (q & 7) + m;
        v = nd3[(size_t)k * 128 + n];
    } else if (f < 144) {
        int q = f - 120; int k = 32 * (q >> 3) + 8 * g + i, n = 16 * (q & 7) + m;
        v = (k < 80) ? ed1[(size_t)k * 128 + n] : (k == 80 ? edb1[n] : 0.f);
    } else {
        int q = f - 144; int k = 32 * (q >> 2) + 8 * g + i, n = 16 * (q & 3) + m;
        v = ed2[(size_t)k * 64 + n] * (edg[k] * BN_K);
    }
    pw[(size_t)f * 512 + t] = f2h(v);
}

// ---------------- generic f16 MFMA GEMM with epilogue (+fused attention dots) ----------------
// MODE 0: raw -> f16 ; 1: relu(+bias) -> f16 ; 2: BN(relu(+bias)) -> f16 ; 3: +bias -> fp32
// AF32: A fp32 converted during staging. NTOT: total n-tiles in pw. DOTS: 0 none,
// 1 = 4-head a_s/a_d dots (NT=8, grid.y=2), 2 = single-head 32-col dots (NT=2).
template <int KC, int NT, int MODE, int AF32, int NTOT, int DOTS>
__global__ __launch_bounds__(256) void k_gemm16(
    const void* __restrict__ Ain, const unsigned short* __restrict__ pwB,
    void* __restrict__ outp, int M,
    const float* __restrict__ bias, const float* __restrict__ g_,
    const float* __restrict__ bb_,
    const float* __restrict__ attS, const float* __restrict__ attD,
    float* __restrict__ a_sO, float* __restrict__ a_dO)
{
    constexpr int K = KC * 32;
    constexpr int LDA = K + 8;
    __shared__ unsigned short s_pw[KC * NT * 512];
    __shared__ unsigned short s_a[64 * LDA];
    __shared__ float s_c[3 * NT * 16];

    int t = threadIdx.x;
    int ttoff = blockIdx.y * NT;
    for (int idx = t; idx < KC * NT * 64; idx += 256) {
        int f = idx >> 6, e8 = idx & 63;
        int c = f / NT, tt = f - c * NT;
        *(half8*)&s_pw[(size_t)idx * 8] =
            *(const half8*)&pwB[(((size_t)(c * NTOT + ttoff + tt)) * 64 + e8) * 8];
    }
    if (MODE) {
        for (int c = t; c < NT * 16; c += 256) {
            s_c[c] = bias[ttoff * 16 + c];
            if (MODE == 2) {
                s_c[NT * 16 + c] = g_[ttoff * 16 + c] * BN_K;
                s_c[2 * NT * 16 + c] = bb_[ttoff * 16 + c];
            }
        }
    }
    int wv = t >> 6, lane = t & 63, gq = lane >> 4, m = lane & 15;

    float asv[NT], adv[NT];
    if (DOTS) {
#pragma unroll
        for (int tt = 0; tt < NT; ++tt) {
            asv[tt] = attS[ttoff * 16 + 16 * tt + m];
            adv[tt] = attD[ttoff * 16 + 16 * tt + m];
        }
    }

    int nrt = (M + 63) >> 6;
    for (int rt = blockIdx.x; rt < nrt; rt += gridDim.x) {
        int r0 = rt << 6;
        __syncthreads();
        for (int idx = t; idx < 64 * (K / 8); idx += 256) {
            int row = idx / (K / 8), cb = idx % (K / 8);
            half8 v = {};
            if (r0 + row < M) {
                if (AF32) {
                    const float* Af = (const float*)Ain + (size_t)(r0 + row) * K + cb * 8;
                    float4 u0 = *(const float4*)Af;
                    float4 u1 = *(const float4*)(Af + 4);
                    union { half8 h; unsigned u[4]; } q;
                    q.u[0] = pkrtz(u0.x, u0.y); q.u[1] = pkrtz(u0.z, u0.w);
                    q.u[2] = pkrtz(u1.x, u1.y); q.u[3] = pkrtz(u1.z, u1.w);
                    v = q.h;
                } else {
                    v = *(const half8*)&((const unsigned short*)Ain)[(size_t)(r0 + row) * K + cb * 8];
                }
            }
            *(half8*)&s_a[row * LDA + cb * 8] = v;
        }
        __syncthreads();
        f32x4 acc[NT] = {};
#pragma unroll
        for (int c = 0; c < KC; ++c) {
            half8 a = *(half8*)&s_a[(wv * 16 + m) * LDA + 32 * c + 8 * gq];
#pragma unroll
            for (int tt = 0; tt < NT; ++tt) {
                half8 b = *(const half8*)&s_pw[(c * NT + tt) * 512 + lane * 8];
                acc[tt] = __builtin_amdgcn_mfma_f32_16x16x32_f16(a, b, acc[tt], 0, 0, 0);
            }
        }
#pragma unroll
        for (int tt = 0; tt < NT; ++tt) {
            int col = 16 * tt + m;
            int ocol = ttoff * 16 + col;
            float cb = MODE ? s_c[col] : 0.f;
#pragma unroll
            for (int r = 0; r < 4; ++r) {
                int row = r0 + wv * 16 + 4 * gq + r;
                float v = acc[tt][r] + cb;
                if (MODE == 1) v = fmaxf(v, 0.f);
                if (MODE == 2) v = fmaxf(v, 0.f) * s_c[NT * 16 + col] + s_c[2 * NT * 16 + col];
                if (MODE == 3) {
                    if (row < M) ((float*)outp)[(size_t)row * (NTOT * 16) + ocol] = v;
                } else {
                    float o = __shfl_xor(v, 1);
                    if (!(m & 1) && row < M)
                        *(unsigned*)&((unsigned short*)outp)[(size_t)row * (NTOT * 16) + ocol] =
                            pkrtz(v, o);
                }
            }
        }
        if (DOTS == 1) {
#pragma unroll
            for (int r = 0; r < 4; ++r) {
                float psA = 0.f, pdA = 0.f, psB = 0.f, pdB = 0.f;
#pragma unroll
                for (int tt = 0; tt < NT && tt < 4; ++tt) {
                    psA = fmaf(acc[tt][r], asv[tt], psA);
                    pdA = fmaf(acc[tt][r], adv[tt], pdA);
                }
#pragma unroll
                for (int tt = 4; tt < NT; ++tt) {
                    psB = fmaf(acc[tt][r], asv[tt], psB);
                    pdB = fmaf(acc[tt][r], adv[tt], pdB);
                }
#pragma unroll
                for (int mm = 1; mm < 16; mm <<= 1) {
                    psA += __shfl_xor(psA, mm); pdA += __shfl_xor(pdA, mm);
                    psB += __shfl_xor(psB, mm); pdB += __shfl_xor(pdB, mm);
                }
                int row = r0 + wv * 16 + 4 * gq + r;
                if (m == 0 && row < M) {
                    int hA = 2 * blockIdx.y;
                    a_sO[(size_t)row * 4 + hA] = psA; a_sO[(size_t)row * 4 + hA + 1] = psB;
                    a_dO[(size_t)row * 4 + hA] = pdA; a_dO[(size_t)row * 4 + hA + 1] = pdB;
                }
            }
        } else if (DOTS == 2) {
#pragma unroll
            for (int r = 0; r < 4; ++r) {
                float ps = 0.f, pd = 0.f;
#pragma unroll
                for (int tt = 0; tt < NT; ++tt) {
                    ps = fmaf(acc[tt][r], asv[tt], ps);
                    pd = fmaf(acc[tt][r], adv[tt], pd);
                }
#pragma unroll
                for (int mm = 1; mm < 16; mm <<= 1) {
                    ps += __shfl_xor(ps, mm); pd += __shfl_xor(pd, mm);
                }
                int row = r0 + wv * 16 + 4 * gq + r;
                if (m == 0 && row < M) { a_sO[row] = ps; a_dO[row] = pd; }
            }
        }
    }
}

// ---------------- GAT layer 0 aggregation: wave per node, src cached, 4x unrolled gather -----
__global__ __launch_bounds__(64) void k_gat0_agg(
    const int* __restrict__ rowptr, const int* __restrict__ col, const int* __restrict__ srcA,
    const float* __restrict__ a_s, const float* __restrict__ a_d, const float* __restrict__ a_e,
    const unsigned short* __restrict__ xw16, const float* __restrict__ b0,
    const float* __restrict__ bng, const float* __restrict__ bnb,
    unsigned short* __restrict__ hout16, int N, int E)
{
    int i = blockIdx.x;
    int lane = threadIdx.x;
    int beg = rowptr[i], end = rowptr[i + 1];
    float ad[4];
#pragma unroll
    for (int h = 0; h < 4; ++h) ad[h] = a_d[(size_t)i * 4 + h];

    float al[4] = {-1e30f, -1e30f, -1e30f, -1e30f};
    int sl0 = i;
    int p0 = beg + lane;
    if (p0 < end) {
        int eid = col[p0];
        sl0 = (eid < E) ? srcA[eid] : i;
        float4 as4 = *(const float4*)(a_s + (size_t)sl0 * 4);
        float4 ae4 = *(const float4*)(a_e + (size_t)eid * 4);
        al[0] = lrelu02(as4.x + ad[0] + ae4.x);
        al[1] = lrelu02(as4.y + ad[1] + ae4.y);
        al[2] = lrelu02(as4.z + ad[2] + ae4.z);
        al[3] = lrelu02(as4.w + ad[3] + ae4.w);
    }
    float mx[4] = {al[0], al[1], al[2], al[3]};
    for (int p = p0 + 64; p < end; p += 64) {
        int eid = col[p];
        int s = (eid < E) ? srcA[eid] : i;
        float4 as4 = *(const float4*)(a_s + (size_t)s * 4);
        float4 ae4 = *(const float4*)(a_e + (size_t)eid * 4);
        mx[0] = fmaxf(mx[0], lrelu02(as4.x + ad[0] + ae4.x));
        mx[1] = fmaxf(mx[1], lrelu02(as4.y + ad[1] + ae4.y));
        mx[2] = fmaxf(mx[2], lrelu02(as4.z + ad[2] + ae4.z));
        mx[3] = fmaxf(mx[3], lrelu02(as4.w + ad[3] + ae4.w));
    }
#pragma unroll
    for (int h = 0; h < 4; ++h)
#pragma unroll
        for (int m = 1; m < 64; m <<= 1) mx[h] = fmaxf(mx[h], __shfl_xor(mx[h], m));

    __shared__ float wls[256];
    __shared__ int s_src[64];
    int hl = lane >> 4;
    float accx = 0.f, accy = 0.f, accz = 0.f, accw = 0.f;
    float s0 = 0.f, s1 = 0.f, s2 = 0.f, s3 = 0.f;
    for (int base = beg; base < end; base += 64) {
        int p = base + lane;
        int cnt = min(64, end - base);
        if (p < end) {
            float aa0, aa1, aa2, aa3;
            int s;
            if (base == beg) {
                s = sl0;
                aa0 = al[0]; aa1 = al[1]; aa2 = al[2]; aa3 = al[3];
            } else {
                int eid = col[p];
                s = (eid < E) ? srcA[eid] : i;
                float4 as4 = *(const float4*)(a_s + (size_t)s * 4);
                float4 ae4 = *(const float4*)(a_e + (size_t)eid * 4);
                aa0 = lrelu02(as4.x + ad[0] + ae4.x);
                aa1 = lrelu02(as4.y + ad[1] + ae4.y);
                aa2 = lrelu02(as4.z + ad[2] + ae4.z);
                aa3 = lrelu02(as4.w + ad[3] + ae4.w);
            }
            float w0 = expf(aa0 - mx[0]);
            float w1 = expf(aa1 - mx[1]);
            float w2 = expf(aa2 - mx[2]);
            float w3 = expf(aa3 - mx[3]);
            s0 += w0; s1 += w1; s2 += w2; s3 += w3;
            wls[lane * 4 + 0] = w0; wls[lane * 4 + 1] = w1;
            wls[lane * 4 + 2] = w2; wls[lane * 4 + 3] = w3;
            s_src[lane] = s;
        }
        __syncthreads();
        int q = 0;
        for (; q + 3 < cnt; q += 4) {
            int ss0 = s_src[q], ss1 = s_src[q + 1], ss2 = s_src[q + 2], ss3 = s_src[q + 3];
            ushort4 x0 = *(const ushort4*)(xw16 + (size_t)ss0 * 256 + lane * 4);
            ushort4 x1 = *(const ushort4*)(xw16 + (size_t)ss1 * 256 + lane * 4);
            ushort4 x2 = *(const ushort4*)(xw16 + (size_t)ss2 * 256 + lane * 4);
            ushort4 x3 = *(const ushort4*)(xw16 + (size_t)ss3 * 256 + lane * 4);
            float w0 = wls[q * 4 + hl], w1 = wls[(q + 1) * 4 + hl];
            float w2 = wls[(q + 2) * 4 + hl], w3 = wls[(q + 3) * 4 + hl];
            accx = fmaf(w0, h2f(x0.x), accx); accy = fmaf(w0, h2f(x0.y), accy);
            accz = fmaf(w0, h2f(x0.z), accz); accw = fmaf(w0, h2f(x0.w), accw);
            accx = fmaf(w1, h2f(x1.x), accx); accy = fmaf(w1, h2f(x1.y), accy);
            accz = fmaf(w1, h2f(x1.z), accz); accw = fmaf(w1, h2f(x1.w), accw);
            accx = fmaf(w2, h2f(x2.x), accx); accy = fmaf(w2, h2f(x2.y), accy);
            accz = fmaf(w2, h2f(x2.z), accz); accw = fmaf(w2, h2f(x2.w), accw);
            accx = fmaf(w3, h2f(x3.x), accx); accy = fmaf(w3, h2f(x3.y), accy);
            accz = fmaf(w3, h2f(x3.z), accz); accw = fmaf(w3, h2f(x3.w), accw);
        }
        for (; q < cnt; ++q) {
            int ss = s_src[q];
            float w = wls[q * 4 + hl];
            ushort4 xv = *(const ushort4*)(xw16 + (size_t)ss * 256 + lane * 4);
            accx = fmaf(w, h2f(xv.x), accx);
            accy = fmaf(w, h2f(xv.y), accy);
            accz = fmaf(w, h2f(xv.z), accz);
            accw = fmaf(w, h2f(xv.w), accw);
        }
        __syncthreads();
    }
#pragma unroll
    for (int m = 1; m < 64; m <<= 1) {
        s0 += __shfl_xor(s0, m); s1 += __shfl_xor(s1, m);
        s2 += __shfl_xor(s2, m); s3 += __shfl_xor(s3, m);
    }
    float sden = ((hl == 0) ? s0 : (hl == 1) ? s1 : (hl == 2) ? s2 : s3) + 1e-16f;

    int ch = lane * 4;
    float out[4] = {accx / sden, accy / sden, accz / sden, accw / sden};
    ushort4 ov;
    unsigned short* po = (unsigned short*)&ov;
#pragma unroll
    for (int j = 0; j < 4; ++j) {
        int c = ch + j;
        float v = out[j] + b0[c];
        v = v * (BN_K * bng[c]) + bnb[c];
        po[j] = f2h((v > 0.f) ? v : expm1f(v));
    }
    *(ushort4*)(hout16 + (size_t)i * 256 + ch) = ov;
}

// ------- GAT layer 1 aggregation v2: 4 edges/wave-step, ushort2 loads, subgroup reduce -------
__global__ __launch_bounds__(64) void k_gat1_agg(
    const int* __restrict__ rowptr, const int* __restrict__ col, const int* __restrict__ srcA,
    const float* __restrict__ a_s, const float* __restrict__ a_d, const float* __restrict__ a_e,
    const unsigned short* __restrict__ xw16, const float* __restrict__ b1,
    float* __restrict__ zout, unsigned short* __restrict__ z16, int N, int E)
{
    int i = blockIdx.x;
    int lane = threadIdx.x;
    int beg = rowptr[i], end = rowptr[i + 1];
    float ad = a_d[i];
    float al = -1e30f;
    int sl0 = i;
    int p0 = beg + lane;
    if (p0 < end) {
        int eid = col[p0];
        sl0 = (eid < E) ? srcA[eid] : i;
        al = lrelu02(a_s[sl0] + ad + a_e[eid]);
    }
    float mx = al;
    for (int p = p0 + 64; p < end; p += 64) {
        int eid = col[p];
        int s = (eid < E) ? srcA[eid] : i;
        mx = fmaxf(mx, lrelu02(a_s[s] + ad + a_e[eid]));
    }
#pragma unroll
    for (int m = 1; m < 64; m <<= 1) mx = fmaxf(mx, __shfl_xor(mx, m));

    __shared__ float wls[64];
    __shared__ int s_src[64];
    float accA = 0.f, accB = 0.f, ssum = 0.f;
    int sub = lane >> 4;          // edge sub-group 0..3
    int ch = (lane & 15) * 2;     // this lane's channel pair
    for (int base = beg; base < end; base += 64) {
        int p = base + lane;
        int cnt = min(64, end - base);
        if (p < end) {
            float aa;
            int s;
            if (base == beg) { s = sl0; aa = al; }
            else {
                int eid = col[p];
                s = (eid < E) ? srcA[eid] : i;
                aa = lrelu02(a_s[s] + ad + a_e[eid]);
            }
            float w = expf(aa - mx);
            ssum += w;
            wls[lane] = w;
            s_src[lane] = s;
        }
        __syncthreads();
        int q = sub;
        for (; q + 12 < cnt; q += 16) {
            int ss0 = s_src[q], ss1 = s_src[q + 4], ss2 = s_src[q + 8], ss3 = s_src[q + 12];
            float w0 = wls[q], w1 = wls[q + 4], w2 = wls[q + 8], w3 = wls[q + 12];
            ushort2 x0 = *(const ushort2*)(xw16 + (size_t)ss0 * 32 + ch);
            ushort2 x1 = *(const ushort2*)(xw16 + (size_t)ss1 * 32 + ch);
            ushort2 x2 = *(const ushort2*)(xw16 + (size_t)ss2 * 32 + ch);
            ushort2 x3 = *(const ushort2*)(xw16 + (size_t)ss3 * 32 + ch);
            accA = fmaf(w0, h2f(x0.x), accA); accB = fmaf(w0, h2f(x0.y), accB);
            accA = fmaf(w1, h2f(x1.x), accA); accB = fmaf(w1, h2f(x1.y), accB);
            accA = fmaf(w2, h2f(x2.x), accA); accB = fmaf(w2, h2f(x2.y), accB);
            accA = fmaf(w3, h2f(x3.x), accA); accB = fmaf(w3, h2f(x3.y), accB);
        }
        for (; q < cnt; q += 4) {
            int ss = s_src[q];
            float w = wls[q];
            ushort2 xv = *(const ushort2*)(xw16 + (size_t)ss * 32 + ch);
            accA = fmaf(w, h2f(xv.x), accA);
            accB = fmaf(w, h2f(xv.y), accB);
        }
        __syncthreads();
    }
#pragma unroll
    for (int m = 1; m < 64; m <<= 1) ssum += __shfl_xor(ssum, m);
    // reduce accumulators across the 4 edge sub-groups (lane bits 4,5)
    accA += __shfl_xor(accA, 16); accB += __shfl_xor(accB, 16);
    accA += __shfl_xor(accA, 32); accB += __shfl_xor(accB, 32);
    if (lane < 16) {
        float inv = 1.f / (ssum + 1e-16f);
        float vA = accA * inv + b1[ch];
        float vB = accB * inv + b1[ch + 1];
        *(float2*)(zout + (size_t)i * 32 + ch) = make_float2(vA, vB);
        *(unsigned*)(z16 + (size_t)i * 32 + ch) = pkrtz(vA, vB);
    }
}

// ------- MFMA edge decoder: proven v3 structure, 8 waves/block for deeper overlap -------
#define H1_STRIDE 136

__global__ __launch_bounds__(512, 4) void k_edge_dec_mfma(
    const unsigned short* __restrict__ z16, const unsigned short* __restrict__ ea16,
    const int* __restrict__ srcA, const int* __restrict__ dstA,
    const unsigned short* __restrict__ pw,  // [0,24)=edW1+b1row, [24,40)=edW2*gscale
    const float* __restrict__ b2p, const float* __restrict__ w3,
    const float* __restrict__ b3v, float* __restrict__ out, int E)
{
    __shared__ unsigned short s_pw[24 * 512];
    __shared__ unsigned short s_h1[8][16 * H1_STRIDE];

    int t = threadIdx.x;
    for (int idx = t; idx < 1536; idx += 512)
        *(half8*)&s_pw[idx * 8] = *(const half8*)&pw[idx * 8];
    __syncthreads();

    int wv = t >> 6, lane = t & 63;
    int g = lane >> 4, m = lane & 15;
    unsigned short* h1 = s_h1[wv];

    half8 w2r[16];
#pragma unroll
    for (int q = 0; q < 16; ++q)
        w2r[q] = *(const half8*)&pw[(size_t)(24 + q) * 512 + lane * 8];

    float w3t[4], b2t[4];
#pragma unroll
    for (int q = 0; q < 4; ++q) { w3t[q] = w3[16 * q + m]; b2t[q] = b2p[16 * q + m]; }
    float b3 = b3v[0];

    int ntiles = (E + 15) >> 4;
    int gw = blockIdx.x * 8 + wv;
    int nw = gridDim.x * 8;

    // prefetch first tile
    half8 a0n = {}, a1n = {}, a2n = {};
    {
        int e = (gw << 4) + m;
        if (gw < ntiles && e < E) {
            int si = srcA[e], di = dstA[e];
            a0n = *(const half8*)&z16[(size_t)si * 32 + 8 * g];
            a1n = *(const half8*)&z16[(size_t)di * 32 + 8 * g];
            if (g < 2) a2n = *(const half8*)&ea16[(size_t)e * 16 + 8 * g];
        }
        if (g == 2) a2n[0] = (_Float16)1.f;  // k=80 constant -> b1 row of edW1
    }

    for (int tile = gw; tile < ntiles; ) {
        half8 a0 = a0n, a1 = a1n, a2 = a2n;
        int e0 = tile << 4;
        int nxt = tile + nw;

        // prefetch next tile (hides under MFMA)
        a0n = half8{}; a1n = half8{}; a2n = half8{};
        {
            int e = (nxt << 4) + m;
            if (nxt < ntiles && e < E) {
                int si = srcA[e], di = dstA[e];
                a0n = *(const half8*)&z16[(size_t)si * 32 + 8 * g];
                a1n = *(const half8*)&z16[(size_t)di * 32 + 8 * g];
                if (g < 2) a2n = *(const half8*)&ea16[(size_t)e * 16 + 8 * g];
            }
            if (g == 2) a2n[0] = (_Float16)1.f;
        }

        // ---- layer 1: [16,96] x [96,128], bias baked in
        f32x4 acc1[8] = {};
#pragma unroll
        for (int tt = 0; tt < 8; ++tt)
            acc1[tt] = __builtin_amdgcn_mfma_f32_16x16x32_f16(a0, *(const half8*)&s_pw[(0 * 8 + tt) * 512 + lane * 8], acc1[tt], 0, 0, 0);
#pragma unroll
        for (int tt = 0; tt < 8; ++tt)
            acc1[tt] = __builtin_amdgcn_mfma_f32_16x16x32_f16(a1, *(const half8*)&s_pw[(1 * 8 + tt) * 512 + lane * 8], acc1[tt], 0, 0, 0);
#pragma unroll
        for (int tt = 0; tt < 8; ++tt)
            acc1[tt] = __builtin_amdgcn_mfma_f32_16x16x32_f16(a2, *(const half8*)&s_pw[(2 * 8 + tt) * 512 + lane * 8], acc1[tt], 0, 0, 0);

        // epilogue: u = relu(acc1) -> f16 packed u32 writes (BN folded into W2/b2p)
#pragma unroll
        for (int tt = 0; tt < 8; ++tt) {
#pragma unroll
            for (int r = 0; r < 4; ++r) {
                float v = fmaxf(acc1[tt][r], 0.f);
                float vo = __shfl_xor(v, 1);
                if (!(m & 1))
                    *(unsigned*)&h1[(4 * g + r) * H1_STRIDE + 16 * tt + m] = pkrtz(v, vo);
            }
        }
        asm volatile("s_waitcnt lgkmcnt(0)" ::: "memory");
        __builtin_amdgcn_sched_barrier(0);

        // ---- layer 2: [16,128] x [128,64] (W2 pre-scaled by BN gamma)
        f32x4 acc2[4] = {};
#pragma unroll
        for (int c = 0; c < 4; ++c) {
            half8 a = *(half8*)&h1[m * H1_STRIDE + 32 * c + 8 * g];
#pragma unroll
            for (int tt = 0; tt < 4; ++tt)
                acc2[tt] = __builtin_amdgcn_mfma_f32_16x16x32_f16(a, w2r[c * 4 + tt], acc2[tt], 0, 0, 0);
        }
        // ---- layer 3: relu(+b2p) dot w3, 16-lane reduce, sigmoid
        float s[4];
#pragma unroll
        for (int r = 0; r < 4; ++r) {
            float acc = 0.f;
#pragma unroll
            for (int tt = 0; tt < 4; ++tt) {
                float v = fmaxf(acc2[tt][r] + b2t[tt], 0.f);
                acc = fmaf(v, w3t[tt], acc);
            }
            acc += __shfl_xor(acc, 1);
            acc += __shfl_xor(acc, 2);
            acc += __shfl_xor(acc, 4);
            acc += __shfl_xor(acc, 8);
            s[r] = acc;
        }
        if (m == 0) {
            int eb = e0 + 4 * g;
            if (eb + 3 < E) {
                float4 o;
                o.x = 1.f / (1.f + expf(-(s[0] + b3)));
                o.y = 1.f / (1.f + expf(-(s[1] + b3)));
                o.z = 1.f / (1.f + expf(-(s[2] + b3)));
                o.w = 1.f / (1.f + expf(-(s[3] + b3)));
                *(float4*)(out + eb) = o;
            } else {
#pragma unroll
                for (int r = 0; r < 4; ++r)
                    if (eb + r < E) out[eb + r] = 1.f / (1.f + expf(-(s[r] + b3)));
            }
        }
        tile = nxt;
    }
}

// =====================================================================================
extern "C" void kernel_launch(void* const* d_in, const int* in_sizes, int n_in,
                              void* d_out, int out_size, void* d_ws, size_t ws_size,
                              hipStream_t stream)
{
    const float* x    = (const float*)d_in[0];
    const float* ea   = (const float*)d_in[1];
    const float* W0   = (const float*)d_in[2];
    const float* We0  = (const float*)d_in[3];
    const float* as0  = (const float*)d_in[4];
    const float* ad0  = (const float*)d_in[5];
    const float* ae0  = (const float*)d_in[6];
    const float* b0   = (const float*)d_in[7];
    const float* bn0g = (const float*)d_in[8];
    const float* bn0b = (const float*)d_in[9];
    const float* W1   = (const float*)d_in[10];
    const float* We1  = (const float*)d_in[11];
    const float* as1  = (const float*)d_in[12];
    const float* ad1  = (const float*)d_in[13];
    const float* ae1  = (const float*)d_in[14];
    const float* b1   = (const float*)d_in[15];
    const float* ndW1 = (const float*)d_in[16];
    const float* ndb1 = (const float*)d_in[17];
    const float* ndg  = (const float*)d_in[18];
    const float* ndbb = (const float*)d_in[19];
    const float* ndW2 = (const float*)d_in[20];
    const float* ndb2 = (const float*)d_in[21];
    const float* ndW3 = (const float*)d_in[22];
    const float* ndb3 = (const float*)d_in[23];
    const float* edW1 = (const float*)d_in[24];
    const float* edb1 = (const float*)d_in[25];
    const float* edg  = (const float*)d_in[26];
    const float* edbb = (const float*)d_in[27];
    const float* edW2 = (const float*)d_in[28];
    const float* edb2 = (const float*)d_in[29];
    const float* edW3 = (const float*)d_in[30];
    const float* edb3 = (const float*)d_in[31];
    const int*   eidx = (const int*)d_in[32];

    const int N = in_sizes[0] / 128;
    const int E = in_sizes[1] / 16;
    const int* srcA = eidx;
    const int* dstA = eidx + E;

    char* ws = (char*)d_ws;
    size_t o = 0;
    auto alloc = [&](size_t bytes) -> void* {
        void* p = ws + o;
        o = (o + bytes + 255) & ~(size_t)255;
        return p;
    };
    typedef unsigned short u16;
    u16*   xw0_16 = (u16*)alloc((size_t)N * 256 * 2);
    u16*   hbuf16 = (u16*)alloc((size_t)N * 256 * 2);
    u16*   xw1_16 = (u16*)alloc((size_t)N * 32 * 2);
    u16*   z16    = (u16*)alloc((size_t)N * 32 * 2);
    u16*   n1_16  = (u16*)alloc((size_t)N * 128 * 2);
    u16*   h2n16  = (u16*)alloc((size_t)N * 64 * 2);
    u16*   ea16   = (u16*)alloc((size_t)E * 16 * 2);
    float* a_s0   = (float*)alloc((size_t)N * 4 * 4);
    float* a_d0   = (float*)alloc((size_t)N * 4 * 4);
    float* a_e0a  = (float*)alloc((size_t)(E + N) * 4 * 4);
    float* a_e1a  = (float*)alloc((size_t)(E + N) * 4);
    float* a_s1   = (float*)alloc((size_t)N * 4);
    float* a_d1   = (float*)alloc((size_t)N * 4);
    int*   deg    = (int*)alloc((size_t)N * 4);
    int*   rowptr = (int*)alloc((size_t)(N + 1) * 4);
    int*   cur    = (int*)alloc((size_t)N * 4);
    int*   col    = (int*)alloc((size_t)(E + N) * 4);
    int*   bsum   = (int*)alloc(64 * 4);
    float* v0     = (float*)alloc(64 * 4);
    float* v1     = (float*)alloc(16 * 4);
    float* b2p    = (float*)alloc(64 * 4);
    u16*   pw     = (u16*)alloc((size_t)160 * 512 * 2);

    float* z_out    = (float*)d_out;
    float* node_out = z_out + (size_t)N * 32;
    float* edge_out = node_out + (size_t)N * 128;

    const int nb = (N + SCHUNK - 1) / SCHUNK;
    const int nrt = (N + 63) / 64;

    // weights / constants / CSR
    k_pack_all<<<160, 512, 0, stream>>>(W0, W1, ndW1, ndW2, ndW3, edW1, edW2, edb1, edg, pw);
    k_ae_vec<<<1, 192, 0, stream>>>(We0, ae0, We1, ae1, edbb, edW2, edb2, v0, v1, b2p);
    k_deg_init<<<(N + 255) / 256, 256, 0, stream>>>(deg, N);
    k_deg_count<<<(E + 255) / 256, 256, 0, stream>>>(dstA, deg, E);
    k_scan1<<<nb, 1024, 0, stream>>>(deg, rowptr, bsum, N);
    k_scan3<<<(N + 255) / 256, 256, 0, stream>>>(bsum, deg, rowptr, cur, N);
    k_fill<<<(E + N + 255) / 256, 256, 0, stream>>>(dstA, cur, col, E, N);
    k_edge_ae<<<(E + 255) / 256, 256, 0, stream>>>(ea, v0, v1, a_e0a, a_e1a, ea16, E);
    k_loop_mean<<<(N + 3) / 4, 256, 0, stream>>>(rowptr, col, ea16, v0, v1, a_e0a, a_e1a, N, E);

    // GAT layer 0 (fp32 x staged, col-split y=2, fused attention dots)
    k_gemm16<4, 8, 0, 1, 16, 1><<<dim3(nrt, 2), 256, 0, stream>>>(
        x, pw, xw0_16, N, nullptr, nullptr, nullptr, as0, ad0, a_s0, a_d0);
    k_gat0_agg<<<N, 64, 0, stream>>>(rowptr, col, srcA, a_s0, a_d0, a_e0a, xw0_16, b0, bn0g, bn0b,
                                     hbuf16, N, E);

    // GAT layer 1 (fused attention dots)
    k_gemm16<8, 2, 0, 0, 2, 2><<<dim3(nrt, 1), 256, 0, stream>>>(
        hbuf16, pw + (size_t)64 * 512, xw1_16, N, nullptr, nullptr, nullptr,
        as1, ad1, a_s1, a_d1);
    k_gat1_agg<<<N, 64, 0, stream>>>(rowptr, col, srcA, a_s1, a_d1, a_e1a, xw1_16, b1,
                                     z_out, z16, N, E);

    // node decoder
    k_gemm16<1, 8, 2, 0, 8, 0><<<dim3(nrt, 1), 256, 0, stream>>>(
        z16, pw + (size_t)80 * 512, n1_16, N, ndb1, ndg, ndbb, nullptr, nullptr, nullptr, nullptr);
    k_gemm16<4, 4, 1, 0, 4, 0><<<dim3(nrt, 1), 256, 0, stream>>>(
        n1_16, pw + (size_t)88 * 512, h2n16, N, ndb2, nullptr, nullptr, nullptr, nullptr, nullptr, nullptr);
    k_gemm16<2, 8, 3, 0, 8, 0><<<dim3(nrt, 1), 256, 0, stream>>>(
        h2n16, pw + (size_t)104 * 512, node_out, N, ndb3, nullptr, nullptr, nullptr, nullptr, nullptr, nullptr);

    // edge decoder: 8 waves/block, 2 blocks/CU (512 blocks = exactly resident)
    k_edge_dec_mfma<<<512, 512, 0, stream>>>(z16, ea16, srcA, dstA, pw + (size_t)120 * 512,
                                             b2p, edW3, edb3, edge_out, E);
}

// Round 11
// 424.851 us; speedup vs baseline: 1.0461x; 1.0461x over previous
//
#include <hip/hip_runtime.h>
#include <math.h>

#define BN_K 0.9999950000374997f  // 1/sqrt(1+1e-5)

static __device__ __forceinline__ float lrelu02(float x) { return x > 0.f ? x : 0.2f * x; }

typedef _Float16 half8 __attribute__((ext_vector_type(8)));
typedef __fp16 fp16x2 __attribute__((ext_vector_type(2)));
typedef float f32x4 __attribute__((ext_vector_type(4)));

static __device__ __forceinline__ unsigned short f2h(float x)
{
    union { _Float16 h; unsigned short u; } q;
    q.h = (_Float16)x;
    return q.u;
}
static __device__ __forceinline__ float h2f(unsigned short u)
{
    union { unsigned short u; _Float16 h; } q;
    q.u = u;
    return (float)q.h;
}
static __device__ __forceinline__ unsigned pkrtz(float a, float b)
{
    union { fp16x2 h; unsigned u; } q;
    q.h = __builtin_amdgcn_cvt_pkrtz(a, b);
    return q.u;
}

// ---- tiny precompute: v0, v1 attention-edge vectors; b2p = edb2 + edbb @ edW2 ----
__global__ void k_ae_vec(const float* __restrict__ We0, const float* __restrict__ ae0,
                         const float* __restrict__ We1, const float* __restrict__ ae1,
                         const float* __restrict__ edbb, const float* __restrict__ edW2,
                         const float* __restrict__ edb2,
                         float* __restrict__ v0, float* __restrict__ v1,
                         float* __restrict__ b2p)
{
    int t = threadIdx.x;
    if (t < 64) {
        int h = t >> 4, k = t & 15;
        float s = 0.f;
        for (int c = 0; c < 64; ++c) s += We0[k * 256 + h * 64 + c] * ae0[h * 64 + c];
        v0[h * 16 + k] = s;
    } else if (t < 80) {
        int k = t - 64;
        float s = 0.f;
        for (int c = 0; c < 32; ++c) s += We1[k * 32 + c] * ae1[c];
        v1[k] = s;
    } else if (t < 144) {
        int n = t - 80;
        float s = 0.f;
        for (int k = 0; k < 128; ++k) s += edbb[k] * edW2[k * 64 + n];
        b2p[n] = edb2[n] + s;
    }
}

// ---------------- CSR build over dst (deg zeroed by memset; +1 self-loop folded in) ----------
__global__ void k_deg_count(const int* __restrict__ dst, int* __restrict__ deg, int E)
{
    int e = blockIdx.x * blockDim.x + threadIdx.x;
    if (e < E) atomicAdd(&deg[dst[e]], 1);
}

#define SCHUNK 4096
__global__ __launch_bounds__(1024) void k_scan1(const int* __restrict__ deg,
                                                int* __restrict__ rowptr,
                                                int* __restrict__ bsum, int n)
{
    __shared__ int sbuf[1024];
    int b = blockIdx.x, t = threadIdx.x;
    int i0 = b * SCHUNK + t * 4;
    int v[4];
#pragma unroll
    for (int j = 0; j < 4; ++j) v[j] = (i0 + j < n) ? deg[i0 + j] + 1 : 0;
    int s = v[0] + v[1] + v[2] + v[3];
    sbuf[t] = s;
    __syncthreads();
    for (int d = 1; d < 1024; d <<= 1) {
        int tmp = (t >= d) ? sbuf[t - d] : 0;
        __syncthreads();
        sbuf[t] += tmp;
        __syncthreads();
    }
    int run = sbuf[t] - s;
#pragma unroll
    for (int j = 0; j < 4; ++j) {
        run += v[j];
        if (i0 + j < n) rowptr[i0 + j + 1] = run;  // chunk-local inclusive
    }
    if (t == 1023) bsum[b] = sbuf[1023];
    if (b == 0 && t == 0) rowptr[0] = 0;
}

__global__ void k_scan3(const int* __restrict__ bsum, const int* __restrict__ deg,
                        int* __restrict__ rowptr, int* __restrict__ cur, int n)
{
    int i = blockIdx.x * blockDim.x + threadIdx.x;
    if (i >= n) return;
    int chunk = i / SCHUNK;
    int off = 0;
    for (int b = 0; b < chunk; ++b) off += bsum[b];
    int r = rowptr[i + 1] + off;
    rowptr[i + 1] = r;
    cur[i] = r - (deg[i] + 1);
}

__global__ void k_fill(const int* __restrict__ dst, int* __restrict__ cur,
                       int* __restrict__ col, int E, int N)
{
    int t = blockIdx.x * blockDim.x + threadIdx.x;
    if (t >= E + N) return;
    int d = (t < E) ? dst[t] : (t - E);
    int slot = atomicAdd(&cur[d], 1);
    col[slot] = t;  // eid: t<E original edge; t=E+i self-loop of node i
}

// ------- self-loop scatter-mean (from ea16) + fused self-loop attention-edge dots -------
__global__ __launch_bounds__(256) void k_loop_mean(
    const int* __restrict__ rowptr, const int* __restrict__ col,
    const unsigned short* __restrict__ ea16,
    const float* __restrict__ v0, const float* __restrict__ v1,
    float* __restrict__ a_e0, float* __restrict__ a_e1, int N, int E)
{
    int wv = threadIdx.x >> 6, lane = threadIdx.x & 63;
    int i = blockIdx.x * 4 + wv;
    if (i >= N) return;
    int beg = rowptr[i], end = rowptr[i + 1];
    int q = lane >> 4, k = lane & 15;
    float sum = 0.f;
    for (int p = beg + q; p < end; p += 4) {
        int eid = col[p];
        if (eid < E) sum += h2f(ea16[(size_t)eid * 16 + k]);
    }
    sum += __shfl_xor(sum, 16);
    sum += __shfl_xor(sum, 32);
    int cnt = end - beg - 1;  // exactly one self-loop per node
    float mean = sum / (float)max(cnt, 1);
    float p0 = mean * v0[q * 16 + k];
    float p1 = mean * v1[k];
#pragma unroll
    for (int mm = 1; mm < 16; mm <<= 1) { p0 += __shfl_xor(p0, mm); p1 += __shfl_xor(p1, mm); }
    if (k == 0) a_e0[(size_t)(E + i) * 4 + q] = p0;
    if (lane == 0) a_e1[E + i] = p1;
}

// ---------------- per-edge attention-edge terms + ea16 emit (original edges only) ------------
__global__ void k_edge_ae(const float* __restrict__ ea,
                          const float* __restrict__ v0, const float* __restrict__ v1,
                          float* __restrict__ a_e0, float* __restrict__ a_e1,
                          unsigned short* __restrict__ ea16, int E)
{
    int idx = blockIdx.x * blockDim.x + threadIdx.x;
    if (idx >= E) return;
    const float* row = ea + (size_t)idx * 16;
    float r[16];
#pragma unroll
    for (int k = 0; k < 16; ++k) r[k] = row[k];
#pragma unroll
    for (int h = 0; h < 4; ++h) {
        float s = 0.f;
#pragma unroll
        for (int k = 0; k < 16; ++k) s = fmaf(r[k], v0[h * 16 + k], s);
        a_e0[(size_t)idx * 4 + h] = s;
    }
    float s1 = 0.f;
#pragma unroll
    for (int k = 0; k < 16; ++k) s1 = fmaf(r[k], v1[k], s1);
    a_e1[idx] = s1;
#pragma unroll
    for (int k = 0; k < 16; k += 4) {
        ushort4 o;
        o.x = f2h(r[k]); o.y = f2h(r[k + 1]); o.z = f2h(r[k + 2]); o.w = f2h(r[k + 3]);
        *(ushort4*)(ea16 + (size_t)idx * 16 + k) = o;
    }
}

// ---------------- pack ALL weights into f16 MFMA fragments ----------------
// sigma(g,i)=8g+i; element (frag f, lane l, i) = W[k=32c+8g+i][n=16t+m], 0 if k>=K.
// frag ranges: [0,64) W0(128,256) c*16+t | [64,80) W1(256,32) c*2+t | [80,88) ndW1(32,128) t
// [88,104) ndW2(128,64) c*4+t | [104,120) ndW3(64,128) c*8+t
// [120,144) edW1(80,128) + bias row at k=80 | [144,160) edW2(128,64) rows scaled by g1*BN_K
__global__ __launch_bounds__(512) void k_pack_all(
    const float* __restrict__ W0, const float* __restrict__ W1,
    const float* __restrict__ nd1, const float* __restrict__ nd2, const float* __restrict__ nd3,
    const float* __restrict__ ed1, const float* __restrict__ ed2,
    const float* __restrict__ edb1, const float* __restrict__ edg,
    unsigned short* __restrict__ pw)
{
    int f = blockIdx.x, t = threadIdx.x;
    int l = t >> 3, i = t & 7, g = l >> 4, m = l & 15;
    float v;
    if (f < 64) {
        int q = f; int k = 32 * (q >> 4) + 8 * g + i, n = 16 * (q & 15) + m;
        v = W0[(size_t)k * 256 + n];
    } else if (f < 80) {
        int q = f - 64; int k = 32 * (q >> 1) + 8 * g + i, n = 16 * (q & 1) + m;
        v = W1[(size_t)k * 32 + n];
    } else if (f < 88) {
        int q = f - 80; int k = 8 * g + i, n = 16 * q + m;
        v = nd1[(size_t)k * 128 + n];
    } else if (f < 104) {
        int q = f - 88; int k = 32 * (q >> 2) + 8 * g + i, n = 16 * (q & 3) + m;
        v = nd2[(size_t)k * 64 + n];
    } else if (f < 120) {
        int q = f - 104; int k = 32 * (q >> 3) + 8 * g + i, n = 16 * (q & 7) + m;
        v = nd3[(size_t)k * 128 + n];
    } else if (f < 144) {
        int q = f - 120; int k = 32 * (q >> 3) + 8 * g + i, n = 16 * (q & 7) + m;
        v = (k < 80) ? ed1[(size_t)k * 128 + n] : (k == 80 ? edb1[n] : 0.f);
    } else {
        int q = f - 144; int k = 32 * (q >> 2) + 8 * g + i, n = 16 * (q & 3) + m;
        v = ed2[(size_t)k * 64 + n] * (edg[k] * BN_K);
    }
    pw[(size_t)f * 512 + t] = f2h(v);
}

// ---------------- generic f16 MFMA GEMM with epilogue (+fused attention dots) ----------------
// MODE 0: raw -> f16 ; 1: relu(+bias) -> f16 ; 2: BN(relu(+bias)) -> f16 ; 3: +bias -> fp32
// AF32: A fp32 converted during staging. NTOT: total n-tiles in pw. DOTS: 0 none,
// 1 = 4-head a_s/a_d dots (NT=8, grid.y=2), 2 = single-head 32-col dots (NT=2).
template <int KC, int NT, int MODE, int AF32, int NTOT, int DOTS>
__global__ __launch_bounds__(256) void k_gemm16(
    const void* __restrict__ Ain, const unsigned short* __restrict__ pwB,
    void* __restrict__ outp, int M,
    const float* __restrict__ bias, const float* __restrict__ g_,
    const float* __restrict__ bb_,
    const float* __restrict__ attS, const float* __restrict__ attD,
    float* __restrict__ a_sO, float* __restrict__ a_dO)
{
    constexpr int K = KC * 32;
    constexpr int LDA = K + 8;
    __shared__ unsigned short s_pw[KC * NT * 512];
    __shared__ unsigned short s_a[64 * LDA];
    __shared__ float s_c[3 * NT * 16];

    int t = threadIdx.x;
    int ttoff = blockIdx.y * NT;
    for (int idx = t; idx < KC * NT * 64; idx += 256) {
        int f = idx >> 6, e8 = idx & 63;
        int c = f / NT, tt = f - c * NT;
        *(half8*)&s_pw[(size_t)idx * 8] =
            *(const half8*)&pwB[(((size_t)(c * NTOT + ttoff + tt)) * 64 + e8) * 8];
    }
    if (MODE) {
        for (int c = t; c < NT * 16; c += 256) {
            s_c[c] = bias[ttoff * 16 + c];
            if (MODE == 2) {
                s_c[NT * 16 + c] = g_[ttoff * 16 + c] * BN_K;
                s_c[2 * NT * 16 + c] = bb_[ttoff * 16 + c];
            }
        }
    }
    int wv = t >> 6, lane = t & 63, gq = lane >> 4, m = lane & 15;

    float asv[NT], adv[NT];
    if (DOTS) {
#pragma unroll
        for (int tt = 0; tt < NT; ++tt) {
            asv[tt] = attS[ttoff * 16 + 16 * tt + m];
            adv[tt] = attD[ttoff * 16 + 16 * tt + m];
        }
    }

    int nrt = (M + 63) >> 6;
    for (int rt = blockIdx.x; rt < nrt; rt += gridDim.x) {
        int r0 = rt << 6;
        __syncthreads();
        for (int idx = t; idx < 64 * (K / 8); idx += 256) {
            int row = idx / (K / 8), cb = idx % (K / 8);
            half8 v = {};
            if (r0 + row < M) {
                if (AF32) {
                    const float* Af = (const float*)Ain + (size_t)(r0 + row) * K + cb * 8;
                    float4 u0 = *(const float4*)Af;
                    float4 u1 = *(const float4*)(Af + 4);
                    union { half8 h; unsigned u[4]; } q;
                    q.u[0] = pkrtz(u0.x, u0.y); q.u[1] = pkrtz(u0.z, u0.w);
                    q.u[2] = pkrtz(u1.x, u1.y); q.u[3] = pkrtz(u1.z, u1.w);
                    v = q.h;
                } else {
                    v = *(const half8*)&((const unsigned short*)Ain)[(size_t)(r0 + row) * K + cb * 8];
                }
            }
            *(half8*)&s_a[row * LDA + cb * 8] = v;
        }
        __syncthreads();
        f32x4 acc[NT] = {};
#pragma unroll
        for (int c = 0; c < KC; ++c) {
            half8 a = *(half8*)&s_a[(wv * 16 + m) * LDA + 32 * c + 8 * gq];
#pragma unroll
            for (int tt = 0; tt < NT; ++tt) {
                half8 b = *(const half8*)&s_pw[(c * NT + tt) * 512 + lane * 8];
                acc[tt] = __builtin_amdgcn_mfma_f32_16x16x32_f16(a, b, acc[tt], 0, 0, 0);
            }
        }
#pragma unroll
        for (int tt = 0; tt < NT; ++tt) {
            int col = 16 * tt + m;
            int ocol = ttoff * 16 + col;
            float cb = MODE ? s_c[col] : 0.f;
#pragma unroll
            for (int r = 0; r < 4; ++r) {
                int row = r0 + wv * 16 + 4 * gq + r;
                float v = acc[tt][r] + cb;
                if (MODE == 1) v = fmaxf(v, 0.f);
                if (MODE == 2) v = fmaxf(v, 0.f) * s_c[NT * 16 + col] + s_c[2 * NT * 16 + col];
                if (MODE == 3) {
                    if (row < M) ((float*)outp)[(size_t)row * (NTOT * 16) + ocol] = v;
                } else {
                    float o = __shfl_xor(v, 1);
                    if (!(m & 1) && row < M)
                        *(unsigned*)&((unsigned short*)outp)[(size_t)row * (NTOT * 16) + ocol] =
                            pkrtz(v, o);
                }
            }
        }
        if (DOTS == 1) {
#pragma unroll
            for (int r = 0; r < 4; ++r) {
                float psA = 0.f, pdA = 0.f, psB = 0.f, pdB = 0.f;
#pragma unroll
                for (int tt = 0; tt < NT && tt < 4; ++tt) {
                    psA = fmaf(acc[tt][r], asv[tt], psA);
                    pdA = fmaf(acc[tt][r], adv[tt], pdA);
                }
#pragma unroll
                for (int tt = 4; tt < NT; ++tt) {
                    psB = fmaf(acc[tt][r], asv[tt], psB);
                    pdB = fmaf(acc[tt][r], adv[tt], pdB);
                }
#pragma unroll
                for (int mm = 1; mm < 16; mm <<= 1) {
                    psA += __shfl_xor(psA, mm); pdA += __shfl_xor(pdA, mm);
                    psB += __shfl_xor(psB, mm); pdB += __shfl_xor(pdB, mm);
                }
                int row = r0 + wv * 16 + 4 * gq + r;
                if (m == 0 && row < M) {
                    int hA = 2 * blockIdx.y;
                    a_sO[(size_t)row * 4 + hA] = psA; a_sO[(size_t)row * 4 + hA + 1] = psB;
                    a_dO[(size_t)row * 4 + hA] = pdA; a_dO[(size_t)row * 4 + hA + 1] = pdB;
                }
            }
        } else if (DOTS == 2) {
#pragma unroll
            for (int r = 0; r < 4; ++r) {
                float ps = 0.f, pd = 0.f;
#pragma unroll
                for (int tt = 0; tt < NT; ++tt) {
                    ps = fmaf(acc[tt][r], asv[tt], ps);
                    pd = fmaf(acc[tt][r], adv[tt], pd);
                }
#pragma unroll
                for (int mm = 1; mm < 16; mm <<= 1) {
                    ps += __shfl_xor(ps, mm); pd += __shfl_xor(pd, mm);
                }
                int row = r0 + wv * 16 + 4 * gq + r;
                if (m == 0 && row < M) { a_sO[row] = ps; a_dO[row] = pd; }
            }
        }
    }
}

// ---------------- GAT layer 0 aggregation: wave per node, src cached, 4x unrolled gather -----
__global__ __launch_bounds__(64) void k_gat0_agg(
    const int* __restrict__ rowptr, const int* __restrict__ col, const int* __restrict__ srcA,
    const float* __restrict__ a_s, const float* __restrict__ a_d, const float* __restrict__ a_e,
    const unsigned short* __restrict__ xw16, const float* __restrict__ b0,
    const float* __restrict__ bng, const float* __restrict__ bnb,
    unsigned short* __restrict__ hout16, int N, int E)
{
    int i = blockIdx.x;
    int lane = threadIdx.x;
    int beg = rowptr[i], end = rowptr[i + 1];
    float ad[4];
#pragma unroll
    for (int h = 0; h < 4; ++h) ad[h] = a_d[(size_t)i * 4 + h];

    float al[4] = {-1e30f, -1e30f, -1e30f, -1e30f};
    int sl0 = i;
    int p0 = beg + lane;
    if (p0 < end) {
        int eid = col[p0];
        sl0 = (eid < E) ? srcA[eid] : i;
        float4 as4 = *(const float4*)(a_s + (size_t)sl0 * 4);
        float4 ae4 = *(const float4*)(a_e + (size_t)eid * 4);
        al[0] = lrelu02(as4.x + ad[0] + ae4.x);
        al[1] = lrelu02(as4.y + ad[1] + ae4.y);
        al[2] = lrelu02(as4.z + ad[2] + ae4.z);
        al[3] = lrelu02(as4.w + ad[3] + ae4.w);
    }
    float mx[4] = {al[0], al[1], al[2], al[3]};
    for (int p = p0 + 64; p < end; p += 64) {
        int eid = col[p];
        int s = (eid < E) ? srcA[eid] : i;
        float4 as4 = *(const float4*)(a_s + (size_t)s * 4);
        float4 ae4 = *(const float4*)(a_e + (size_t)eid * 4);
        mx[0] = fmaxf(mx[0], lrelu02(as4.x + ad[0] + ae4.x));
        mx[1] = fmaxf(mx[1], lrelu02(as4.y + ad[1] + ae4.y));
        mx[2] = fmaxf(mx[2], lrelu02(as4.z + ad[2] + ae4.z));
        mx[3] = fmaxf(mx[3], lrelu02(as4.w + ad[3] + ae4.w));
    }
#pragma unroll
    for (int h = 0; h < 4; ++h)
#pragma unroll
        for (int m = 1; m < 64; m <<= 1) mx[h] = fmaxf(mx[h], __shfl_xor(mx[h], m));

    __shared__ float wls[256];
    __shared__ int s_src[64];
    int hl = lane >> 4;
    float accx = 0.f, accy = 0.f, accz = 0.f, accw = 0.f;
    float s0 = 0.f, s1 = 0.f, s2 = 0.f, s3 = 0.f;
    for (int base = beg; base < end; base += 64) {
        int p = base + lane;
        int cnt = min(64, end - base);
        if (p < end) {
            float aa0, aa1, aa2, aa3;
            int s;
            if (base == beg) {
                s = sl0;
                aa0 = al[0]; aa1 = al[1]; aa2 = al[2]; aa3 = al[3];
            } else {
                int eid = col[p];
                s = (eid < E) ? srcA[eid] : i;
                float4 as4 = *(const float4*)(a_s + (size_t)s * 4);
                float4 ae4 = *(const float4*)(a_e + (size_t)eid * 4);
                aa0 = lrelu02(as4.x + ad[0] + ae4.x);
                aa1 = lrelu02(as4.y + ad[1] + ae4.y);
                aa2 = lrelu02(as4.z + ad[2] + ae4.z);
                aa3 = lrelu02(as4.w + ad[3] + ae4.w);
            }
            float w0 = expf(aa0 - mx[0]);
            float w1 = expf(aa1 - mx[1]);
            float w2 = expf(aa2 - mx[2]);
            float w3 = expf(aa3 - mx[3]);
            s0 += w0; s1 += w1; s2 += w2; s3 += w3;
            wls[lane * 4 + 0] = w0; wls[lane * 4 + 1] = w1;
            wls[lane * 4 + 2] = w2; wls[lane * 4 + 3] = w3;
            s_src[lane] = s;
        }
        __syncthreads();
        int q = 0;
        for (; q + 3 < cnt; q += 4) {
            int ss0 = s_src[q], ss1 = s_src[q + 1], ss2 = s_src[q + 2], ss3 = s_src[q + 3];
            ushort4 x0 = *(const ushort4*)(xw16 + (size_t)ss0 * 256 + lane * 4);
            ushort4 x1 = *(const ushort4*)(xw16 + (size_t)ss1 * 256 + lane * 4);
            ushort4 x2 = *(const ushort4*)(xw16 + (size_t)ss2 * 256 + lane * 4);
            ushort4 x3 = *(const ushort4*)(xw16 + (size_t)ss3 * 256 + lane * 4);
            float w0 = wls[q * 4 + hl], w1 = wls[(q + 1) * 4 + hl];
            float w2 = wls[(q + 2) * 4 + hl], w3 = wls[(q + 3) * 4 + hl];
            accx = fmaf(w0, h2f(x0.x), accx); accy = fmaf(w0, h2f(x0.y), accy);
            accz = fmaf(w0, h2f(x0.z), accz); accw = fmaf(w0, h2f(x0.w), accw);
            accx = fmaf(w1, h2f(x1.x), accx); accy = fmaf(w1, h2f(x1.y), accy);
            accz = fmaf(w1, h2f(x1.z), accz); accw = fmaf(w1, h2f(x1.w), accw);
            accx = fmaf(w2, h2f(x2.x), accx); accy = fmaf(w2, h2f(x2.y), accy);
            accz = fmaf(w2, h2f(x2.z), accz); accw = fmaf(w2, h2f(x2.w), accw);
            accx = fmaf(w3, h2f(x3.x), accx); accy = fmaf(w3, h2f(x3.y), accy);
            accz = fmaf(w3, h2f(x3.z), accz); accw = fmaf(w3, h2f(x3.w), accw);
        }
        for (; q < cnt; ++q) {
            int ss = s_src[q];
            float w = wls[q * 4 + hl];
            ushort4 xv = *(const ushort4*)(xw16 + (size_t)ss * 256 + lane * 4);
            accx = fmaf(w, h2f(xv.x), accx);
            accy = fmaf(w, h2f(xv.y), accy);
            accz = fmaf(w, h2f(xv.z), accz);
            accw = fmaf(w, h2f(xv.w), accw);
        }
        __syncthreads();
    }
#pragma unroll
    for (int m = 1; m < 64; m <<= 1) {
        s0 += __shfl_xor(s0, m); s1 += __shfl_xor(s1, m);
        s2 += __shfl_xor(s2, m); s3 += __shfl_xor(s3, m);
    }
    float sden = ((hl == 0) ? s0 : (hl == 1) ? s1 : (hl == 2) ? s2 : s3) + 1e-16f;

    int ch = lane * 4;
    float out[4] = {accx / sden, accy / sden, accz / sden, accw / sden};
    ushort4 ov;
    unsigned short* po = (unsigned short*)&ov;
#pragma unroll
    for (int j = 0; j < 4; ++j) {
        int c = ch + j;
        float v = out[j] + b0[c];
        v = v * (BN_K * bng[c]) + bnb[c];
        po[j] = f2h((v > 0.f) ? v : expm1f(v));
    }
    *(ushort4*)(hout16 + (size_t)i * 256 + ch) = ov;
}

// ------- GAT layer 1 aggregation v2: 4 edges/wave-step, ushort2 loads, subgroup reduce -------
__global__ __launch_bounds__(64) void k_gat1_agg(
    const int* __restrict__ rowptr, const int* __restrict__ col, const int* __restrict__ srcA,
    const float* __restrict__ a_s, const float* __restrict__ a_d, const float* __restrict__ a_e,
    const unsigned short* __restrict__ xw16, const float* __restrict__ b1,
    float* __restrict__ zout, unsigned short* __restrict__ z16, int N, int E)
{
    int i = blockIdx.x;
    int lane = threadIdx.x;
    int beg = rowptr[i], end = rowptr[i + 1];
    float ad = a_d[i];
    float al = -1e30f;
    int sl0 = i;
    int p0 = beg + lane;
    if (p0 < end) {
        int eid = col[p0];
        sl0 = (eid < E) ? srcA[eid] : i;
        al = lrelu02(a_s[sl0] + ad + a_e[eid]);
    }
    float mx = al;
    for (int p = p0 + 64; p < end; p += 64) {
        int eid = col[p];
        int s = (eid < E) ? srcA[eid] : i;
        mx = fmaxf(mx, lrelu02(a_s[s] + ad + a_e[eid]));
    }
#pragma unroll
    for (int m = 1; m < 64; m <<= 1) mx = fmaxf(mx, __shfl_xor(mx, m));

    __shared__ float wls[64];
    __shared__ int s_src[64];
    float accA = 0.f, accB = 0.f, ssum = 0.f;
    int sub = lane >> 4;          // edge sub-group 0..3
    int ch = (lane & 15) * 2;     // this lane's channel pair
    for (int base = beg; base < end; base += 64) {
        int p = base + lane;
        int cnt = min(64, end - base);
        if (p < end) {
            float aa;
            int s;
            if (base == beg) { s = sl0; aa = al; }
            else {
                int eid = col[p];
                s = (eid < E) ? srcA[eid] : i;
                aa = lrelu02(a_s[s] + ad + a_e[eid]);
            }
            float w = expf(aa - mx);
            ssum += w;
            wls[lane] = w;
            s_src[lane] = s;
        }
        __syncthreads();
        int q = sub;
        for (; q + 12 < cnt; q += 16) {
            int ss0 = s_src[q], ss1 = s_src[q + 4], ss2 = s_src[q + 8], ss3 = s_src[q + 12];
            float w0 = wls[q], w1 = wls[q + 4], w2 = wls[q + 8], w3 = wls[q + 12];
            ushort2 x0 = *(const ushort2*)(xw16 + (size_t)ss0 * 32 + ch);
            ushort2 x1 = *(const ushort2*)(xw16 + (size_t)ss1 * 32 + ch);
            ushort2 x2 = *(const ushort2*)(xw16 + (size_t)ss2 * 32 + ch);
            ushort2 x3 = *(const ushort2*)(xw16 + (size_t)ss3 * 32 + ch);
            accA = fmaf(w0, h2f(x0.x), accA); accB = fmaf(w0, h2f(x0.y), accB);
            accA = fmaf(w1, h2f(x1.x), accA); accB = fmaf(w1, h2f(x1.y), accB);
            accA = fmaf(w2, h2f(x2.x), accA); accB = fmaf(w2, h2f(x2.y), accB);
            accA = fmaf(w3, h2f(x3.x), accA); accB = fmaf(w3, h2f(x3.y), accB);
        }
        for (; q < cnt; q += 4) {
            int ss = s_src[q];
            float w = wls[q];
            ushort2 xv = *(const ushort2*)(xw16 + (size_t)ss * 32 + ch);
            accA = fmaf(w, h2f(xv.x), accA);
            accB = fmaf(w, h2f(xv.y), accB);
        }
        __syncthreads();
    }
#pragma unroll
    for (int m = 1; m < 64; m <<= 1) ssum += __shfl_xor(ssum, m);
    accA += __shfl_xor(accA, 16); accB += __shfl_xor(accB, 16);
    accA += __shfl_xor(accA, 32); accB += __shfl_xor(accB, 32);
    if (lane < 16) {
        float inv = 1.f / (ssum + 1e-16f);
        float vA = accA * inv + b1[ch];
        float vB = accB * inv + b1[ch + 1];
        *(float2*)(zout + (size_t)i * 32 + ch) = make_float2(vA, vB);
        *(unsigned*)(z16 + (size_t)i * 32 + ch) = pkrtz(vA, vB);
    }
}

// ---------------- MFMA edge decoder (proven v3): bias/BN folded, prefetch, h1 via LDS --------
#define H1_STRIDE 136

__global__ __launch_bounds__(256, 3) void k_edge_dec_mfma(
    const unsigned short* __restrict__ z16, const unsigned short* __restrict__ ea16,
    const int* __restrict__ srcA, const int* __restrict__ dstA,
    const unsigned short* __restrict__ pw,  // [0,24)=edW1+b1row, [24,40)=edW2*gscale
    const float* __restrict__ b2p, const float* __restrict__ w3,
    const float* __restrict__ b3v, float* __restrict__ out, int E)
{
    __shared__ unsigned short s_pw[24 * 512];
    __shared__ unsigned short s_h1[4][16 * H1_STRIDE];

    int t = threadIdx.x;
    for (int idx = t; idx < 1536; idx += 256)
        *(half8*)&s_pw[idx * 8] = *(const half8*)&pw[idx * 8];
    __syncthreads();

    int wv = t >> 6, lane = t & 63;
    int g = lane >> 4, m = lane & 15;
    unsigned short* h1 = s_h1[wv];

    half8 w2r[16];
#pragma unroll
    for (int q = 0; q < 16; ++q)
        w2r[q] = *(const half8*)&pw[(size_t)(24 + q) * 512 + lane * 8];

    float w3t[4], b2t[4];
#pragma unroll
    for (int q = 0; q < 4; ++q) { w3t[q] = w3[16 * q + m]; b2t[q] = b2p[16 * q + m]; }
    float b3 = b3v[0];

    int ntiles = (E + 15) >> 4;
    int gw = blockIdx.x * 4 + wv;
    int nw = gridDim.x * 4;

    // prefetch first tile
    half8 a0n = {}, a1n = {}, a2n = {};
    {
        int e = (gw << 4) + m;
        if (gw < ntiles && e < E) {
            int si = srcA[e], di = dstA[e];
            a0n = *(const half8*)&z16[(size_t)si * 32 + 8 * g];
            a1n = *(const half8*)&z16[(size_t)di * 32 + 8 * g];
            if (g < 2) a2n = *(const half8*)&ea16[(size_t)e * 16 + 8 * g];
        }
        if (g == 2) a2n[0] = (_Float16)1.f;  // k=80 constant -> b1 row of edW1
    }

    for (int tile = gw; tile < ntiles; ) {
        half8 a0 = a0n, a1 = a1n, a2 = a2n;
        int e0 = tile << 4;
        int nxt = tile + nw;

        // prefetch next tile (hides under MFMA)
        a0n = half8{}; a1n = half8{}; a2n = half8{};
        {
            int e = (nxt << 4) + m;
            if (nxt < ntiles && e < E) {
                int si = srcA[e], di = dstA[e];
                a0n = *(const half8*)&z16[(size_t)si * 32 + 8 * g];
                a1n = *(const half8*)&z16[(size_t)di * 32 + 8 * g];
                if (g < 2) a2n = *(const half8*)&ea16[(size_t)e * 16 + 8 * g];
            }
            if (g == 2) a2n[0] = (_Float16)1.f;
        }

        // ---- layer 1: [16,96] x [96,128], bias baked in
        f32x4 acc1[8] = {};
#pragma unroll
        for (int tt = 0; tt < 8; ++tt)
            acc1[tt] = __builtin_amdgcn_mfma_f32_16x16x32_f16(a0, *(const half8*)&s_pw[(0 * 8 + tt) * 512 + lane * 8], acc1[tt], 0, 0, 0);
#pragma unroll
        for (int tt = 0; tt < 8; ++tt)
            acc1[tt] = __builtin_amdgcn_mfma_f32_16x16x32_f16(a1, *(const half8*)&s_pw[(1 * 8 + tt) * 512 + lane * 8], acc1[tt], 0, 0, 0);
#pragma unroll
        for (int tt = 0; tt < 8; ++tt)
            acc1[tt] = __builtin_amdgcn_mfma_f32_16x16x32_f16(a2, *(const half8*)&s_pw[(2 * 8 + tt) * 512 + lane * 8], acc1[tt], 0, 0, 0);

        // epilogue: u = relu(acc1) -> f16 packed u32 writes (BN folded into W2/b2p)
#pragma unroll
        for (int tt = 0; tt < 8; ++tt) {
#pragma unroll
            for (int r = 0; r < 4; ++r) {
                float v = fmaxf(acc1[tt][r], 0.f);
                float vo = __shfl_xor(v, 1);
                if (!(m & 1))
                    *(unsigned*)&h1[(4 * g + r) * H1_STRIDE + 16 * tt + m] = pkrtz(v, vo);
            }
        }
        asm volatile("s_waitcnt lgkmcnt(0)" ::: "memory");
        __builtin_amdgcn_sched_barrier(0);

        // ---- layer 2: [16,128] x [128,64] (W2 pre-scaled by BN gamma)
        f32x4 acc2[4] = {};
#pragma unroll
        for (int c = 0; c < 4; ++c) {
            half8 a = *(half8*)&h1[m * H1_STRIDE + 32 * c + 8 * g];
#pragma unroll
            for (int tt = 0; tt < 4; ++tt)
                acc2[tt] = __builtin_amdgcn_mfma_f32_16x16x32_f16(a, w2r[c * 4 + tt], acc2[tt], 0, 0, 0);
        }
        // ---- layer 3: relu(+b2p) dot w3, 16-lane reduce, sigmoid
        float s[4];
#pragma unroll
        for (int r = 0; r < 4; ++r) {
            float acc = 0.f;
#pragma unroll
            for (int tt = 0; tt < 4; ++tt) {
                float v = fmaxf(acc2[tt][r] + b2t[tt], 0.f);
                acc = fmaf(v, w3t[tt], acc);
            }
            acc += __shfl_xor(acc, 1);
            acc += __shfl_xor(acc, 2);
            acc += __shfl_xor(acc, 4);
            acc += __shfl_xor(acc, 8);
            s[r] = acc;
        }
        if (m == 0) {
            int eb = e0 + 4 * g;
            if (eb + 3 < E) {
                float4 o;
                o.x = 1.f / (1.f + expf(-(s[0] + b3)));
                o.y = 1.f / (1.f + expf(-(s[1] + b3)));
                o.z = 1.f / (1.f + expf(-(s[2] + b3)));
                o.w = 1.f / (1.f + expf(-(s[3] + b3)));
                *(float4*)(out + eb) = o;
            } else {
#pragma unroll
                for (int r = 0; r < 4; ++r)
                    if (eb + r < E) out[eb + r] = 1.f / (1.f + expf(-(s[r] + b3)));
            }
        }
        tile = nxt;
    }
}

// =====================================================================================
extern "C" void kernel_launch(void* const* d_in, const int* in_sizes, int n_in,
                              void* d_out, int out_size, void* d_ws, size_t ws_size,
                              hipStream_t stream)
{
    const float* x    = (const float*)d_in[0];
    const float* ea   = (const float*)d_in[1];
    const float* W0   = (const float*)d_in[2];
    const float* We0  = (const float*)d_in[3];
    const float* as0  = (const float*)d_in[4];
    const float* ad0  = (const float*)d_in[5];
    const float* ae0  = (const float*)d_in[6];
    const float* b0   = (const float*)d_in[7];
    const float* bn0g = (const float*)d_in[8];
    const float* bn0b = (const float*)d_in[9];
    const float* W1   = (const float*)d_in[10];
    const float* We1  = (const float*)d_in[11];
    const float* as1  = (const float*)d_in[12];
    const float* ad1  = (const float*)d_in[13];
    const float* ae1  = (const float*)d_in[14];
    const float* b1   = (const float*)d_in[15];
    const float* ndW1 = (const float*)d_in[16];
    const float* ndb1 = (const float*)d_in[17];
    const float* ndg  = (const float*)d_in[18];
    const float* ndbb = (const float*)d_in[19];
    const float* ndW2 = (const float*)d_in[20];
    const float* ndb2 = (const float*)d_in[21];
    const float* ndW3 = (const float*)d_in[22];
    const float* ndb3 = (const float*)d_in[23];
    const float* edW1 = (const float*)d_in[24];
    const float* edb1 = (const float*)d_in[25];
    const float* edg  = (const float*)d_in[26];
    const float* edbb = (const float*)d_in[27];
    const float* edW2 = (const float*)d_in[28];
    const float* edb2 = (const float*)d_in[29];
    const float* edW3 = (const float*)d_in[30];
    const float* edb3 = (const float*)d_in[31];
    const int*   eidx = (const int*)d_in[32];

    const int N = in_sizes[0] / 128;
    const int E = in_sizes[1] / 16;
    const int* srcA = eidx;
    const int* dstA = eidx + E;

    char* ws = (char*)d_ws;
    size_t o = 0;
    auto alloc = [&](size_t bytes) -> void* {
        void* p = ws + o;
        o = (o + bytes + 255) & ~(size_t)255;
        return p;
    };
    typedef unsigned short u16;
    u16*   xw0_16 = (u16*)alloc((size_t)N * 256 * 2);
    u16*   hbuf16 = (u16*)alloc((size_t)N * 256 * 2);
    u16*   xw1_16 = (u16*)alloc((size_t)N * 32 * 2);
    u16*   z16    = (u16*)alloc((size_t)N * 32 * 2);
    u16*   n1_16  = (u16*)alloc((size_t)N * 128 * 2);
    u16*   h2n16  = (u16*)alloc((size_t)N * 64 * 2);
    u16*   ea16   = (u16*)alloc((size_t)E * 16 * 2);
    float* a_s0   = (float*)alloc((size_t)N * 4 * 4);
    float* a_d0   = (float*)alloc((size_t)N * 4 * 4);
    float* a_e0a  = (float*)alloc((size_t)(E + N) * 4 * 4);
    float* a_e1a  = (float*)alloc((size_t)(E + N) * 4);
    float* a_s1   = (float*)alloc((size_t)N * 4);
    float* a_d1   = (float*)alloc((size_t)N * 4);
    int*   deg    = (int*)alloc((size_t)N * 4);
    int*   rowptr = (int*)alloc((size_t)(N + 1) * 4);
    int*   cur    = (int*)alloc((size_t)N * 4);
    int*   col    = (int*)alloc((size_t)(E + N) * 4);
    int*   bsum   = (int*)alloc(64 * 4);
    float* v0     = (float*)alloc(64 * 4);
    float* v1     = (float*)alloc(16 * 4);
    float* b2p    = (float*)alloc(64 * 4);
    u16*   pw     = (u16*)alloc((size_t)160 * 512 * 2);

    float* z_out    = (float*)d_out;
    float* node_out = z_out + (size_t)N * 32;
    float* edge_out = node_out + (size_t)N * 128;

    const int nb = (N + SCHUNK - 1) / SCHUNK;
    const int nrt = (N + 63) / 64;

    // weights / constants / CSR
    hipMemsetAsync(deg, 0, (size_t)N * 4, stream);
    k_pack_all<<<160, 512, 0, stream>>>(W0, W1, ndW1, ndW2, ndW3, edW1, edW2, edb1, edg, pw);
    k_ae_vec<<<1, 192, 0, stream>>>(We0, ae0, We1, ae1, edbb, edW2, edb2, v0, v1, b2p);
    k_deg_count<<<(E + 255) / 256, 256, 0, stream>>>(dstA, deg, E);
    k_scan1<<<nb, 1024, 0, stream>>>(deg, rowptr, bsum, N);
    k_scan3<<<(N + 255) / 256, 256, 0, stream>>>(bsum, deg, rowptr, cur, N);
    k_fill<<<(E + N + 255) / 256, 256, 0, stream>>>(dstA, cur, col, E, N);
    k_edge_ae<<<(E + 255) / 256, 256, 0, stream>>>(ea, v0, v1, a_e0a, a_e1a, ea16, E);
    k_loop_mean<<<(N + 3) / 4, 256, 0, stream>>>(rowptr, col, ea16, v0, v1, a_e0a, a_e1a, N, E);

    // GAT layer 0 (fp32 x staged, col-split y=2, fused attention dots)
    k_gemm16<4, 8, 0, 1, 16, 1><<<dim3(nrt, 2), 256, 0, stream>>>(
        x, pw, xw0_16, N, nullptr, nullptr, nullptr, as0, ad0, a_s0, a_d0);
    k_gat0_agg<<<N, 64, 0, stream>>>(rowptr, col, srcA, a_s0, a_d0, a_e0a, xw0_16, b0, bn0g, bn0b,
                                     hbuf16, N, E);

    // GAT layer 1 (fused attention dots)
    k_gemm16<8, 2, 0, 0, 2, 2><<<dim3(nrt, 1), 256, 0, stream>>>(
        hbuf16, pw + (size_t)64 * 512, xw1_16, N, nullptr, nullptr, nullptr,
        as1, ad1, a_s1, a_d1);
    k_gat1_agg<<<N, 64, 0, stream>>>(rowptr, col, srcA, a_s1, a_d1, a_e1a, xw1_16, b1,
                                     z_out, z16, N, E);

    // node decoder
    k_gemm16<1, 8, 2, 0, 8, 0><<<dim3(nrt, 1), 256, 0, stream>>>(
        z16, pw + (size_t)80 * 512, n1_16, N, ndb1, ndg, ndbb, nullptr, nullptr, nullptr, nullptr);
    k_gemm16<4, 4, 1, 0, 4, 0><<<dim3(nrt, 1), 256, 0, stream>>>(
        n1_16, pw + (size_t)88 * 512, h2n16, N, ndb2, nullptr, nullptr, nullptr, nullptr, nullptr, nullptr);
    k_gemm16<2, 8, 3, 0, 8, 0><<<dim3(nrt, 1), 256, 0, stream>>>(
        h2n16, pw + (size_t)104 * 512, node_out, N, ndb3, nullptr, nullptr, nullptr, nullptr, nullptr, nullptr);

    // edge decoder (proven config: 256 thr, 3 blocks/CU, 768 blocks)
    k_edge_dec_mfma<<<768, 256, 0, stream>>>(z16, ea16, srcA, dstA, pw + (size_t)120 * 512,
                                             b2p, edW3, edb3, edge_out, E);
}

// Round 12
// 405.374 us; speedup vs baseline: 1.0964x; 1.0480x over previous
//
#include <hip/hip_runtime.h>
#include <math.h>

#define BN_K 0.9999950000374997f  // 1/sqrt(1+1e-5)

static __device__ __forceinline__ float lrelu02(float x) { return x > 0.f ? x : 0.2f * x; }

typedef _Float16 half8 __attribute__((ext_vector_type(8)));
typedef __fp16 fp16x2 __attribute__((ext_vector_type(2)));
typedef float f32x4 __attribute__((ext_vector_type(4)));

static __device__ __forceinline__ unsigned short f2h(float x)
{
    union { _Float16 h; unsigned short u; } q;
    q.h = (_Float16)x;
    return q.u;
}
static __device__ __forceinline__ float h2f(unsigned short u)
{
    union { unsigned short u; _Float16 h; } q;
    q.u = u;
    return (float)q.h;
}
static __device__ __forceinline__ unsigned pkrtz(float a, float b)
{
    union { fp16x2 h; unsigned u; } q;
    q.h = __builtin_amdgcn_cvt_pkrtz(a, b);
    return q.u;
}

// ---------------- CSR helpers ----------------
#define SCHUNK 4096
__global__ __launch_bounds__(1024) void k_scan1(const int* __restrict__ deg,
                                                int* __restrict__ rowptr,
                                                int* __restrict__ bsum, int n)
{
    __shared__ int sbuf[1024];
    int b = blockIdx.x, t = threadIdx.x;
    int i0 = b * SCHUNK + t * 4;
    int v[4];
#pragma unroll
    for (int j = 0; j < 4; ++j) v[j] = (i0 + j < n) ? deg[i0 + j] + 1 : 0;
    int s = v[0] + v[1] + v[2] + v[3];
    sbuf[t] = s;
    __syncthreads();
    for (int d = 1; d < 1024; d <<= 1) {
        int tmp = (t >= d) ? sbuf[t - d] : 0;
        __syncthreads();
        sbuf[t] += tmp;
        __syncthreads();
    }
    int run = sbuf[t] - s;
#pragma unroll
    for (int j = 0; j < 4; ++j) {
        run += v[j];
        if (i0 + j < n) rowptr[i0 + j + 1] = run;  // chunk-local inclusive
    }
    if (t == 1023) bsum[b] = sbuf[1023];
    if (b == 0 && t == 0) rowptr[0] = 0;
}

__global__ void k_scan3(const int* __restrict__ bsum, const int* __restrict__ deg,
                        int* __restrict__ rowptr, int* __restrict__ cur, int n)
{
    int i = blockIdx.x * blockDim.x + threadIdx.x;
    if (i >= n) return;
    int chunk = i / SCHUNK;
    int off = 0;
    for (int b = 0; b < chunk; ++b) off += bsum[b];
    int r = rowptr[i + 1] + off;
    rowptr[i + 1] = r;
    cur[i] = r - (deg[i] + 1);
}

__global__ void k_fill(const int* __restrict__ dst, int* __restrict__ cur,
                       int* __restrict__ col, int E, int N)
{
    int t = blockIdx.x * blockDim.x + threadIdx.x;
    if (t >= E + N) return;
    int d = (t < E) ? dst[t] : (t - E);
    int slot = atomicAdd(&cur[d], 1);
    col[slot] = t;  // eid: t<E original edge; t=E+i self-loop of node i
}

// ------- self-loop scatter-mean (from ea16) + fused self-loop attention-edge dots -------
__global__ __launch_bounds__(256) void k_loop_mean(
    const int* __restrict__ rowptr, const int* __restrict__ col,
    const unsigned short* __restrict__ ea16,
    const float* __restrict__ v0, const float* __restrict__ v1,
    float* __restrict__ a_e0, float* __restrict__ a_e1, int N, int E)
{
    int wv = threadIdx.x >> 6, lane = threadIdx.x & 63;
    int i = blockIdx.x * 4 + wv;
    if (i >= N) return;
    int beg = rowptr[i], end = rowptr[i + 1];
    int q = lane >> 4, k = lane & 15;
    float sum = 0.f;
    for (int p = beg + q; p < end; p += 4) {
        int eid = col[p];
        if (eid < E) sum += h2f(ea16[(size_t)eid * 16 + k]);
    }
    sum += __shfl_xor(sum, 16);
    sum += __shfl_xor(sum, 32);
    int cnt = end - beg - 1;  // exactly one self-loop per node
    float mean = sum / (float)max(cnt, 1);
    float p0 = mean * v0[q * 16 + k];
    float p1 = mean * v1[k];
#pragma unroll
    for (int mm = 1; mm < 16; mm <<= 1) { p0 += __shfl_xor(p0, mm); p1 += __shfl_xor(p1, mm); }
    if (k == 0) a_e0[(size_t)(E + i) * 4 + q] = p0;
    if (lane == 0) a_e1[E + i] = p1;
}

// ---- per-edge attention-edge terms + ea16 emit + fused deg count (original edges) ----
__global__ void k_edge_ae(const float* __restrict__ ea,
                          const float* __restrict__ v0, const float* __restrict__ v1,
                          const int* __restrict__ dstA, int* __restrict__ deg,
                          float* __restrict__ a_e0, float* __restrict__ a_e1,
                          unsigned short* __restrict__ ea16, int E)
{
    int idx = blockIdx.x * blockDim.x + threadIdx.x;
    if (idx >= E) return;
    atomicAdd(&deg[dstA[idx]], 1);
    const float* row = ea + (size_t)idx * 16;
    float r[16];
#pragma unroll
    for (int k = 0; k < 16; ++k) r[k] = row[k];
#pragma unroll
    for (int h = 0; h < 4; ++h) {
        float s = 0.f;
#pragma unroll
        for (int k = 0; k < 16; ++k) s = fmaf(r[k], v0[h * 16 + k], s);
        a_e0[(size_t)idx * 4 + h] = s;
    }
    float s1 = 0.f;
#pragma unroll
    for (int k = 0; k < 16; ++k) s1 = fmaf(r[k], v1[k], s1);
    a_e1[idx] = s1;
#pragma unroll
    for (int k = 0; k < 16; k += 4) {
        ushort4 o;
        o.x = f2h(r[k]); o.y = f2h(r[k + 1]); o.z = f2h(r[k + 2]); o.w = f2h(r[k + 3]);
        *(ushort4*)(ea16 + (size_t)idx * 16 + k) = o;
    }
}

// ---------------- pack ALL weights into f16 MFMA fragments (+ block 160 = tiny precompute) ---
// sigma(g,i)=8g+i; element (frag f, lane l, i) = W[k=32c+8g+i][n=16t+m], 0 if k>=K.
// frag ranges: [0,64) W0(128,256) c*16+t | [64,80) W1(256,32) c*2+t | [80,88) ndW1(32,128) t
// [88,104) ndW2(128,64) c*4+t | [104,120) ndW3(64,128) c*8+t
// [120,144) edW1(80,128) + bias row at k=80 | [144,160) edW2(128,64) rows scaled by g1*BN_K
__global__ __launch_bounds__(512) void k_pack_all(
    const float* __restrict__ W0, const float* __restrict__ W1,
    const float* __restrict__ nd1, const float* __restrict__ nd2, const float* __restrict__ nd3,
    const float* __restrict__ ed1, const float* __restrict__ ed2,
    const float* __restrict__ edb1, const float* __restrict__ edg,
    const float* __restrict__ We0, const float* __restrict__ ae0,
    const float* __restrict__ We1, const float* __restrict__ ae1,
    const float* __restrict__ edbb, const float* __restrict__ edb2,
    unsigned short* __restrict__ pw,
    float* __restrict__ v0, float* __restrict__ v1, float* __restrict__ b2p)
{
    int f = blockIdx.x, t = threadIdx.x;
    if (f == 160) {  // tiny precompute: v0, v1, b2p
        if (t < 64) {
            int h = t >> 4, k = t & 15;
            float s = 0.f;
            for (int c = 0; c < 64; ++c) s += We0[k * 256 + h * 64 + c] * ae0[h * 64 + c];
            v0[h * 16 + k] = s;
        } else if (t < 80) {
            int k = t - 64;
            float s = 0.f;
            for (int c = 0; c < 32; ++c) s += We1[k * 32 + c] * ae1[c];
            v1[k] = s;
        } else if (t < 144) {
            int n = t - 80;
            float s = 0.f;
            for (int k = 0; k < 128; ++k) s += edbb[k] * ed2[k * 64 + n];
            b2p[n] = edb2[n] + s;
        }
        return;
    }
    int l = t >> 3, i = t & 7, g = l >> 4, m = l & 15;
    float v;
    if (f < 64) {
        int q = f; int k = 32 * (q >> 4) + 8 * g + i, n = 16 * (q & 15) + m;
        v = W0[(size_t)k * 256 + n];
    } else if (f < 80) {
        int q = f - 64; int k = 32 * (q >> 1) + 8 * g + i, n = 16 * (q & 1) + m;
        v = W1[(size_t)k * 32 + n];
    } else if (f < 88) {
        int q = f - 80; int k = 8 * g + i, n = 16 * q + m;
        v = nd1[(size_t)k * 128 + n];
    } else if (f < 104) {
        int q = f - 88; int k = 32 * (q >> 2) + 8 * g + i, n = 16 * (q & 3) + m;
        v = nd2[(size_t)k * 64 + n];
    } else if (f < 120) {
        int q = f - 104; int k = 32 * (q >> 3) + 8 * g + i, n = 16 * (q & 7) + m;
        v = nd3[(size_t)k * 128 + n];
    } else if (f < 144) {
        int q = f - 120; int k = 32 * (q >> 3) + 8 * g + i, n = 16 * (q & 7) + m;
        v = (k < 80) ? ed1[(size_t)k * 128 + n] : (k == 80 ? edb1[n] : 0.f);
    } else {
        int q = f - 144; int k = 32 * (q >> 2) + 8 * g + i, n = 16 * (q & 3) + m;
        v = ed2[(size_t)k * 64 + n] * (edg[k] * BN_K);
    }
    pw[(size_t)f * 512 + t] = f2h(v);
}

// ---------------- generic f16 MFMA GEMM with epilogue (+fused attention dots) ----------------
// MODE 0: raw -> f16. DOTS: 1 = 4-head a_s/a_d dots (NT=8, grid.y=2), 2 = single-head (NT=2).
template <int KC, int NT, int MODE, int AF32, int NTOT, int DOTS>
__global__ __launch_bounds__(256) void k_gemm16(
    const void* __restrict__ Ain, const unsigned short* __restrict__ pwB,
    void* __restrict__ outp, int M,
    const float* __restrict__ bias, const float* __restrict__ g_,
    const float* __restrict__ bb_,
    const float* __restrict__ attS, const float* __restrict__ attD,
    float* __restrict__ a_sO, float* __restrict__ a_dO)
{
    constexpr int K = KC * 32;
    constexpr int LDA = K + 8;
    __shared__ unsigned short s_pw[KC * NT * 512];
    __shared__ unsigned short s_a[64 * LDA];
    __shared__ float s_c[3 * NT * 16];

    int t = threadIdx.x;
    int ttoff = blockIdx.y * NT;
    for (int idx = t; idx < KC * NT * 64; idx += 256) {
        int f = idx >> 6, e8 = idx & 63;
        int c = f / NT, tt = f - c * NT;
        *(half8*)&s_pw[(size_t)idx * 8] =
            *(const half8*)&pwB[(((size_t)(c * NTOT + ttoff + tt)) * 64 + e8) * 8];
    }
    if (MODE) {
        for (int c = t; c < NT * 16; c += 256) {
            s_c[c] = bias[ttoff * 16 + c];
            if (MODE == 2) {
                s_c[NT * 16 + c] = g_[ttoff * 16 + c] * BN_K;
                s_c[2 * NT * 16 + c] = bb_[ttoff * 16 + c];
            }
        }
    }
    int wv = t >> 6, lane = t & 63, gq = lane >> 4, m = lane & 15;

    float asv[NT], adv[NT];
    if (DOTS) {
#pragma unroll
        for (int tt = 0; tt < NT; ++tt) {
            asv[tt] = attS[ttoff * 16 + 16 * tt + m];
            adv[tt] = attD[ttoff * 16 + 16 * tt + m];
        }
    }

    int nrt = (M + 63) >> 6;
    for (int rt = blockIdx.x; rt < nrt; rt += gridDim.x) {
        int r0 = rt << 6;
        __syncthreads();
        for (int idx = t; idx < 64 * (K / 8); idx += 256) {
            int row = idx / (K / 8), cb = idx % (K / 8);
            half8 v = {};
            if (r0 + row < M) {
                if (AF32) {
                    const float* Af = (const float*)Ain + (size_t)(r0 + row) * K + cb * 8;
                    float4 u0 = *(const float4*)Af;
                    float4 u1 = *(const float4*)(Af + 4);
                    union { half8 h; unsigned u[4]; } q;
                    q.u[0] = pkrtz(u0.x, u0.y); q.u[1] = pkrtz(u0.z, u0.w);
                    q.u[2] = pkrtz(u1.x, u1.y); q.u[3] = pkrtz(u1.z, u1.w);
                    v = q.h;
                } else {
                    v = *(const half8*)&((const unsigned short*)Ain)[(size_t)(r0 + row) * K + cb * 8];
                }
            }
            *(half8*)&s_a[row * LDA + cb * 8] = v;
        }
        __syncthreads();
        f32x4 acc[NT] = {};
#pragma unroll
        for (int c = 0; c < KC; ++c) {
            half8 a = *(half8*)&s_a[(wv * 16 + m) * LDA + 32 * c + 8 * gq];
#pragma unroll
            for (int tt = 0; tt < NT; ++tt) {
                half8 b = *(const half8*)&s_pw[(c * NT + tt) * 512 + lane * 8];
                acc[tt] = __builtin_amdgcn_mfma_f32_16x16x32_f16(a, b, acc[tt], 0, 0, 0);
            }
        }
#pragma unroll
        for (int tt = 0; tt < NT; ++tt) {
            int col = 16 * tt + m;
            int ocol = ttoff * 16 + col;
            float cb = MODE ? s_c[col] : 0.f;
#pragma unroll
            for (int r = 0; r < 4; ++r) {
                int row = r0 + wv * 16 + 4 * gq + r;
                float v = acc[tt][r] + cb;
                if (MODE == 1) v = fmaxf(v, 0.f);
                if (MODE == 2) v = fmaxf(v, 0.f) * s_c[NT * 16 + col] + s_c[2 * NT * 16 + col];
                if (MODE == 3) {
                    if (row < M) ((float*)outp)[(size_t)row * (NTOT * 16) + ocol] = v;
                } else {
                    float o = __shfl_xor(v, 1);
                    if (!(m & 1) && row < M)
                        *(unsigned*)&((unsigned short*)outp)[(size_t)row * (NTOT * 16) + ocol] =
                            pkrtz(v, o);
                }
            }
        }
        if (DOTS == 1) {
#pragma unroll
            for (int r = 0; r < 4; ++r) {
                float psA = 0.f, pdA = 0.f, psB = 0.f, pdB = 0.f;
#pragma unroll
                for (int tt = 0; tt < NT && tt < 4; ++tt) {
                    psA = fmaf(acc[tt][r], asv[tt], psA);
                    pdA = fmaf(acc[tt][r], adv[tt], pdA);
                }
#pragma unroll
                for (int tt = 4; tt < NT; ++tt) {
                    psB = fmaf(acc[tt][r], asv[tt], psB);
                    pdB = fmaf(acc[tt][r], adv[tt], pdB);
                }
#pragma unroll
                for (int mm = 1; mm < 16; mm <<= 1) {
                    psA += __shfl_xor(psA, mm); pdA += __shfl_xor(pdA, mm);
                    psB += __shfl_xor(psB, mm); pdB += __shfl_xor(pdB, mm);
                }
                int row = r0 + wv * 16 + 4 * gq + r;
                if (m == 0 && row < M) {
                    int hA = 2 * blockIdx.y;
                    a_sO[(size_t)row * 4 + hA] = psA; a_sO[(size_t)row * 4 + hA + 1] = psB;
                    a_dO[(size_t)row * 4 + hA] = pdA; a_dO[(size_t)row * 4 + hA + 1] = pdB;
                }
            }
        } else if (DOTS == 2) {
#pragma unroll
            for (int r = 0; r < 4; ++r) {
                float ps = 0.f, pd = 0.f;
#pragma unroll
                for (int tt = 0; tt < NT; ++tt) {
                    ps = fmaf(acc[tt][r], asv[tt], ps);
                    pd = fmaf(acc[tt][r], adv[tt], pd);
                }
#pragma unroll
                for (int mm = 1; mm < 16; mm <<= 1) {
                    ps += __shfl_xor(ps, mm); pd += __shfl_xor(pd, mm);
                }
                int row = r0 + wv * 16 + 4 * gq + r;
                if (m == 0 && row < M) { a_sO[row] = ps; a_dO[row] = pd; }
            }
        }
    }
}

// ---------------- GAT layer 0 aggregation: wave per node, src cached, 4x unrolled gather -----
__global__ __launch_bounds__(64) void k_gat0_agg(
    const int* __restrict__ rowptr, const int* __restrict__ col, const int* __restrict__ srcA,
    const float* __restrict__ a_s, const float* __restrict__ a_d, const float* __restrict__ a_e,
    const unsigned short* __restrict__ xw16, const float* __restrict__ b0,
    const float* __restrict__ bng, const float* __restrict__ bnb,
    unsigned short* __restrict__ hout16, int N, int E)
{
    int i = blockIdx.x;
    int lane = threadIdx.x;
    int beg = rowptr[i], end = rowptr[i + 1];
    float ad[4];
#pragma unroll
    for (int h = 0; h < 4; ++h) ad[h] = a_d[(size_t)i * 4 + h];

    float al[4] = {-1e30f, -1e30f, -1e30f, -1e30f};
    int sl0 = i;
    int p0 = beg + lane;
    if (p0 < end) {
        int eid = col[p0];
        sl0 = (eid < E) ? srcA[eid] : i;
        float4 as4 = *(const float4*)(a_s + (size_t)sl0 * 4);
        float4 ae4 = *(const float4*)(a_e + (size_t)eid * 4);
        al[0] = lrelu02(as4.x + ad[0] + ae4.x);
        al[1] = lrelu02(as4.y + ad[1] + ae4.y);
        al[2] = lrelu02(as4.z + ad[2] + ae4.z);
        al[3] = lrelu02(as4.w + ad[3] + ae4.w);
    }
    float mx[4] = {al[0], al[1], al[2], al[3]};
    for (int p = p0 + 64; p < end; p += 64) {
        int eid = col[p];
        int s = (eid < E) ? srcA[eid] : i;
        float4 as4 = *(const float4*)(a_s + (size_t)s * 4);
        float4 ae4 = *(const float4*)(a_e + (size_t)eid * 4);
        mx[0] = fmaxf(mx[0], lrelu02(as4.x + ad[0] + ae4.x));
        mx[1] = fmaxf(mx[1], lrelu02(as4.y + ad[1] + ae4.y));
        mx[2] = fmaxf(mx[2], lrelu02(as4.z + ad[2] + ae4.z));
        mx[3] = fmaxf(mx[3], lrelu02(as4.w + ad[3] + ae4.w));
    }
#pragma unroll
    for (int h = 0; h < 4; ++h)
#pragma unroll
        for (int m = 1; m < 64; m <<= 1) mx[h] = fmaxf(mx[h], __shfl_xor(mx[h], m));

    __shared__ float wls[256];
    __shared__ int s_src[64];
    int hl = lane >> 4;
    float accx = 0.f, accy = 0.f, accz = 0.f, accw = 0.f;
    float s0 = 0.f, s1 = 0.f, s2 = 0.f, s3 = 0.f;
    for (int base = beg; base < end; base += 64) {
        int p = base + lane;
        int cnt = min(64, end - base);
        if (p < end) {
            float aa0, aa1, aa2, aa3;
            int s;
            if (base == beg) {
                s = sl0;
                aa0 = al[0]; aa1 = al[1]; aa2 = al[2]; aa3 = al[3];
            } else {
                int eid = col[p];
                s = (eid < E) ? srcA[eid] : i;
                float4 as4 = *(const float4*)(a_s + (size_t)s * 4);
                float4 ae4 = *(const float4*)(a_e + (size_t)eid * 4);
                aa0 = lrelu02(as4.x + ad[0] + ae4.x);
                aa1 = lrelu02(as4.y + ad[1] + ae4.y);
                aa2 = lrelu02(as4.z + ad[2] + ae4.z);
                aa3 = lrelu02(as4.w + ad[3] + ae4.w);
            }
            float w0 = expf(aa0 - mx[0]);
            float w1 = expf(aa1 - mx[1]);
            float w2 = expf(aa2 - mx[2]);
            float w3 = expf(aa3 - mx[3]);
            s0 += w0; s1 += w1; s2 += w2; s3 += w3;
            wls[lane * 4 + 0] = w0; wls[lane * 4 + 1] = w1;
            wls[lane * 4 + 2] = w2; wls[lane * 4 + 3] = w3;
            s_src[lane] = s;
        }
        __syncthreads();
        int q = 0;
        for (; q + 3 < cnt; q += 4) {
            int ss0 = s_src[q], ss1 = s_src[q + 1], ss2 = s_src[q + 2], ss3 = s_src[q + 3];
            ushort4 x0 = *(const ushort4*)(xw16 + (size_t)ss0 * 256 + lane * 4);
            ushort4 x1 = *(const ushort4*)(xw16 + (size_t)ss1 * 256 + lane * 4);
            ushort4 x2 = *(const ushort4*)(xw16 + (size_t)ss2 * 256 + lane * 4);
            ushort4 x3 = *(const ushort4*)(xw16 + (size_t)ss3 * 256 + lane * 4);
            float w0 = wls[q * 4 + hl], w1 = wls[(q + 1) * 4 + hl];
            float w2 = wls[(q + 2) * 4 + hl], w3 = wls[(q + 3) * 4 + hl];
            accx = fmaf(w0, h2f(x0.x), accx); accy = fmaf(w0, h2f(x0.y), accy);
            accz = fmaf(w0, h2f(x0.z), accz); accw = fmaf(w0, h2f(x0.w), accw);
            accx = fmaf(w1, h2f(x1.x), accx); accy = fmaf(w1, h2f(x1.y), accy);
            accz = fmaf(w1, h2f(x1.z), accz); accw = fmaf(w1, h2f(x1.w), accw);
            accx = fmaf(w2, h2f(x2.x), accx); accy = fmaf(w2, h2f(x2.y), accy);
            accz = fmaf(w2, h2f(x2.z), accz); accw = fmaf(w2, h2f(x2.w), accw);
            accx = fmaf(w3, h2f(x3.x), accx); accy = fmaf(w3, h2f(x3.y), accy);
            accz = fmaf(w3, h2f(x3.z), accz); accw = fmaf(w3, h2f(x3.w), accw);
        }
        for (; q < cnt; ++q) {
            int ss = s_src[q];
            float w = wls[q * 4 + hl];
            ushort4 xv = *(const ushort4*)(xw16 + (size_t)ss * 256 + lane * 4);
            accx = fmaf(w, h2f(xv.x), accx);
            accy = fmaf(w, h2f(xv.y), accy);
            accz = fmaf(w, h2f(xv.z), accz);
            accw = fmaf(w, h2f(xv.w), accw);
        }
        __syncthreads();
    }
#pragma unroll
    for (int m = 1; m < 64; m <<= 1) {
        s0 += __shfl_xor(s0, m); s1 += __shfl_xor(s1, m);
        s2 += __shfl_xor(s2, m); s3 += __shfl_xor(s3, m);
    }
    float sden = ((hl == 0) ? s0 : (hl == 1) ? s1 : (hl == 2) ? s2 : s3) + 1e-16f;

    int ch = lane * 4;
    float out[4] = {accx / sden, accy / sden, accz / sden, accw / sden};
    ushort4 ov;
    unsigned short* po = (unsigned short*)&ov;
#pragma unroll
    for (int j = 0; j < 4; ++j) {
        int c = ch + j;
        float v = out[j] + b0[c];
        v = v * (BN_K * bng[c]) + bnb[c];
        po[j] = f2h((v > 0.f) ? v : expm1f(v));
    }
    *(ushort4*)(hout16 + (size_t)i * 256 + ch) = ov;
}

// ------- GAT layer 1 aggregation v2: 4 edges/wave-step, ushort2 loads, subgroup reduce -------
__global__ __launch_bounds__(64) void k_gat1_agg(
    const int* __restrict__ rowptr, const int* __restrict__ col, const int* __restrict__ srcA,
    const float* __restrict__ a_s, const float* __restrict__ a_d, const float* __restrict__ a_e,
    const unsigned short* __restrict__ xw16, const float* __restrict__ b1,
    float* __restrict__ zout, unsigned short* __restrict__ z16, int N, int E)
{
    int i = blockIdx.x;
    int lane = threadIdx.x;
    int beg = rowptr[i], end = rowptr[i + 1];
    float ad = a_d[i];
    float al = -1e30f;
    int sl0 = i;
    int p0 = beg + lane;
    if (p0 < end) {
        int eid = col[p0];
        sl0 = (eid < E) ? srcA[eid] : i;
        al = lrelu02(a_s[sl0] + ad + a_e[eid]);
    }
    float mx = al;
    for (int p = p0 + 64; p < end; p += 64) {
        int eid = col[p];
        int s = (eid < E) ? srcA[eid] : i;
        mx = fmaxf(mx, lrelu02(a_s[s] + ad + a_e[eid]));
    }
#pragma unroll
    for (int m = 1; m < 64; m <<= 1) mx = fmaxf(mx, __shfl_xor(mx, m));

    __shared__ float wls[64];
    __shared__ int s_src[64];
    float accA = 0.f, accB = 0.f, ssum = 0.f;
    int sub = lane >> 4;          // edge sub-group 0..3
    int ch = (lane & 15) * 2;     // this lane's channel pair
    for (int base = beg; base < end; base += 64) {
        int p = base + lane;
        int cnt = min(64, end - base);
        if (p < end) {
            float aa;
            int s;
            if (base == beg) { s = sl0; aa = al; }
            else {
                int eid = col[p];
                s = (eid < E) ? srcA[eid] : i;
                aa = lrelu02(a_s[s] + ad + a_e[eid]);
            }
            float w = expf(aa - mx);
            ssum += w;
            wls[lane] = w;
            s_src[lane] = s;
        }
        __syncthreads();
        int q = sub;
        for (; q + 12 < cnt; q += 16) {
            int ss0 = s_src[q], ss1 = s_src[q + 4], ss2 = s_src[q + 8], ss3 = s_src[q + 12];
            float w0 = wls[q], w1 = wls[q + 4], w2 = wls[q + 8], w3 = wls[q + 12];
            ushort2 x0 = *(const ushort2*)(xw16 + (size_t)ss0 * 32 + ch);
            ushort2 x1 = *(const ushort2*)(xw16 + (size_t)ss1 * 32 + ch);
            ushort2 x2 = *(const ushort2*)(xw16 + (size_t)ss2 * 32 + ch);
            ushort2 x3 = *(const ushort2*)(xw16 + (size_t)ss3 * 32 + ch);
            accA = fmaf(w0, h2f(x0.x), accA); accB = fmaf(w0, h2f(x0.y), accB);
            accA = fmaf(w1, h2f(x1.x), accA); accB = fmaf(w1, h2f(x1.y), accB);
            accA = fmaf(w2, h2f(x2.x), accA); accB = fmaf(w2, h2f(x2.y), accB);
            accA = fmaf(w3, h2f(x3.x), accA); accB = fmaf(w3, h2f(x3.y), accB);
        }
        for (; q < cnt; q += 4) {
            int ss = s_src[q];
            float w = wls[q];
            ushort2 xv = *(const ushort2*)(xw16 + (size_t)ss * 32 + ch);
            accA = fmaf(w, h2f(xv.x), accA);
            accB = fmaf(w, h2f(xv.y), accB);
        }
        __syncthreads();
    }
#pragma unroll
    for (int m = 1; m < 64; m <<= 1) ssum += __shfl_xor(ssum, m);
    accA += __shfl_xor(accA, 16); accB += __shfl_xor(accB, 16);
    accA += __shfl_xor(accA, 32); accB += __shfl_xor(accB, 32);
    if (lane < 16) {
        float inv = 1.f / (ssum + 1e-16f);
        float vA = accA * inv + b1[ch];
        float vB = accB * inv + b1[ch + 1];
        *(float2*)(zout + (size_t)i * 32 + ch) = make_float2(vA, vB);
        *(unsigned*)(z16 + (size_t)i * 32 + ch) = pkrtz(vA, vB);
    }
}

// ------- fused node decoder: z16 -> BN(relu(@nd1)) -> relu(@nd2) -> @nd3 + b (fp32) -------
#define N1_STRIDE 136
#define H2_STRIDE 72

__global__ __launch_bounds__(256, 2) void k_node_dec(
    const unsigned short* __restrict__ z16, const unsigned short* __restrict__ pw,  // nd frags
    const float* __restrict__ b1, const float* __restrict__ g1, const float* __restrict__ bb1,
    const float* __restrict__ b2, const float* __restrict__ b3,
    float* __restrict__ out, int N)
{
    __shared__ unsigned short s_pw[40 * 512];          // nd1[0,8) nd2[8,24) nd3[24,40)
    __shared__ unsigned short s_z[64 * 40];
    __shared__ unsigned short s_n1[4][16 * N1_STRIDE];
    __shared__ unsigned short s_h2[4][16 * H2_STRIDE];
    __shared__ float s_c[128 * 3 + 64 + 128];          // b1|g1k|bb1|b2|b3

    int t = threadIdx.x;
    for (int idx = t; idx < 2560; idx += 256)
        *(half8*)&s_pw[idx * 8] = *(const half8*)&pw[idx * 8];
    if (t < 128) {
        s_c[t] = b1[t];
        s_c[128 + t] = g1[t] * BN_K;
        s_c[256 + t] = bb1[t];
        s_c[448 + t] = b3[t];
    }
    if (t < 64) s_c[384 + t] = b2[t];
    __syncthreads();

    int wv = t >> 6, lane = t & 63;
    int g = lane >> 4, m = lane & 15;
    unsigned short* n1 = s_n1[wv];
    unsigned short* h2 = s_h2[wv];

    int nrt = (N + 63) >> 6;
    for (int rt = blockIdx.x; rt < nrt; rt += gridDim.x) {
        int r0 = rt << 6;
        __syncthreads();
        {   // stage z tile: 64 rows x 32 f16; 256 threads x 1 half8
            int row = t >> 2, cb = t & 3;
            half8 v = {};
            if (r0 + row < N) v = *(const half8*)&z16[(size_t)(r0 + row) * 32 + cb * 8];
            *(half8*)&s_z[row * 40 + cb * 8] = v;
        }
        __syncthreads();

        // ---- L1: [16,32] x [32,128] -> n1 (BN(relu(+b1))), per-wave rows wv*16..+16
        f32x4 acc1[8] = {};
        {
            half8 a = *(half8*)&s_z[(wv * 16 + m) * 40 + 8 * g];
#pragma unroll
            for (int tt = 0; tt < 8; ++tt)
                acc1[tt] = __builtin_amdgcn_mfma_f32_16x16x32_f16(
                    a, *(const half8*)&s_pw[tt * 512 + lane * 8], acc1[tt], 0, 0, 0);
        }
#pragma unroll
        for (int tt = 0; tt < 8; ++tt) {
            int col = 16 * tt + m;
            float cb = s_c[col], cg = s_c[128 + col], cbb = s_c[256 + col];
#pragma unroll
            for (int r = 0; r < 4; ++r) {
                float v = fmaxf(acc1[tt][r] + cb, 0.f) * cg + cbb;
                float vo = __shfl_xor(v, 1);
                if (!(m & 1))
                    *(unsigned*)&n1[(4 * g + r) * N1_STRIDE + 16 * tt + m] = pkrtz(v, vo);
            }
        }
        asm volatile("s_waitcnt lgkmcnt(0)" ::: "memory");
        __builtin_amdgcn_sched_barrier(0);

        // ---- L2: [16,128] x [128,64] -> h2 (relu(+b2))
        f32x4 acc2[4] = {};
#pragma unroll
        for (int c = 0; c < 4; ++c) {
            half8 a = *(half8*)&n1[m * N1_STRIDE + 32 * c + 8 * g];
#pragma unroll
            for (int tt = 0; tt < 4; ++tt)
                acc2[tt] = __builtin_amdgcn_mfma_f32_16x16x32_f16(
                    a, *(const half8*)&s_pw[(8 + c * 4 + tt) * 512 + lane * 8], acc2[tt], 0, 0, 0);
        }
#pragma unroll
        for (int tt = 0; tt < 4; ++tt) {
            int col = 16 * tt + m;
            float cb = s_c[384 + col];
#pragma unroll
            for (int r = 0; r < 4; ++r) {
                float v = fmaxf(acc2[tt][r] + cb, 0.f);
                float vo = __shfl_xor(v, 1);
                if (!(m & 1))
                    *(unsigned*)&h2[(4 * g + r) * H2_STRIDE + 16 * tt + m] = pkrtz(v, vo);
            }
        }
        asm volatile("s_waitcnt lgkmcnt(0)" ::: "memory");
        __builtin_amdgcn_sched_barrier(0);

        // ---- L3: [16,64] x [64,128] -> out fp32 (+b3)
        f32x4 acc3[8] = {};
#pragma unroll
        for (int c = 0; c < 2; ++c) {
            half8 a = *(half8*)&h2[m * H2_STRIDE + 32 * c + 8 * g];
#pragma unroll
            for (int tt = 0; tt < 8; ++tt)
                acc3[tt] = __builtin_amdgcn_mfma_f32_16x16x32_f16(
                    a, *(const half8*)&s_pw[(24 + c * 8 + tt) * 512 + lane * 8], acc3[tt], 0, 0, 0);
        }
#pragma unroll
        for (int tt = 0; tt < 8; ++tt) {
            int col = 16 * tt + m;
            float cb = s_c[448 + col];
#pragma unroll
            for (int r = 0; r < 4; ++r) {
                int row = r0 + wv * 16 + 4 * g + r;
                if (row < N) out[(size_t)row * 128 + col] = acc3[tt][r] + cb;
            }
        }
    }
}

// ---------------- MFMA edge decoder (proven v3): bias/BN folded, prefetch, h1 via LDS --------
#define H1_STRIDE 136

__global__ __launch_bounds__(256, 3) void k_edge_dec_mfma(
    const unsigned short* __restrict__ z16, const unsigned short* __restrict__ ea16,
    const int* __restrict__ srcA, const int* __restrict__ dstA,
    const unsigned short* __restrict__ pw,  // [0,24)=edW1+b1row, [24,40)=edW2*gscale
    const float* __restrict__ b2p, const float* __restrict__ w3,
    const float* __restrict__ b3v, float* __restrict__ out, int E)
{
    __shared__ unsigned short s_pw[24 * 512];
    __shared__ unsigned short s_h1[4][16 * H1_STRIDE];

    int t = threadIdx.x;
    for (int idx = t; idx < 1536; idx += 256)
        *(half8*)&s_pw[idx * 8] = *(const half8*)&pw[idx * 8];
    __syncthreads();

    int wv = t >> 6, lane = t & 63;
    int g = lane >> 4, m = lane & 15;
    unsigned short* h1 = s_h1[wv];

    half8 w2r[16];
#pragma unroll
    for (int q = 0; q < 16; ++q)
        w2r[q] = *(const half8*)&pw[(size_t)(24 + q) * 512 + lane * 8];

    float w3t[4], b2t[4];
#pragma unroll
    for (int q = 0; q < 4; ++q) { w3t[q] = w3[16 * q + m]; b2t[q] = b2p[16 * q + m]; }
    float b3 = b3v[0];

    int ntiles = (E + 15) >> 4;
    int gw = blockIdx.x * 4 + wv;
    int nw = gridDim.x * 4;

    // prefetch first tile
    half8 a0n = {}, a1n = {}, a2n = {};
    {
        int e = (gw << 4) + m;
        if (gw < ntiles && e < E) {
            int si = srcA[e], di = dstA[e];
            a0n = *(const half8*)&z16[(size_t)si * 32 + 8 * g];
            a1n = *(const half8*)&z16[(size_t)di * 32 + 8 * g];
            if (g < 2) a2n = *(const half8*)&ea16[(size_t)e * 16 + 8 * g];
        }
        if (g == 2) a2n[0] = (_Float16)1.f;  // k=80 constant -> b1 row of edW1
    }

    for (int tile = gw; tile < ntiles; ) {
        half8 a0 = a0n, a1 = a1n, a2 = a2n;
        int e0 = tile << 4;
        int nxt = tile + nw;

        // prefetch next tile (hides under MFMA)
        a0n = half8{}; a1n = half8{}; a2n = half8{};
        {
            int e = (nxt << 4) + m;
            if (nxt < ntiles && e < E) {
                int si = srcA[e], di = dstA[e];
                a0n = *(const half8*)&z16[(size_t)si * 32 + 8 * g];
                a1n = *(const half8*)&z16[(size_t)di * 32 + 8 * g];
                if (g < 2) a2n = *(const half8*)&ea16[(size_t)e * 16 + 8 * g];
            }
            if (g == 2) a2n[0] = (_Float16)1.f;
        }

        // ---- layer 1: [16,96] x [96,128], bias baked in
        f32x4 acc1[8] = {};
#pragma unroll
        for (int tt = 0; tt < 8; ++tt)
            acc1[tt] = __builtin_amdgcn_mfma_f32_16x16x32_f16(a0, *(const half8*)&s_pw[(0 * 8 + tt) * 512 + lane * 8], acc1[tt], 0, 0, 0);
#pragma unroll
        for (int tt = 0; tt < 8; ++tt)
            acc1[tt] = __builtin_amdgcn_mfma_f32_16x16x32_f16(a1, *(const half8*)&s_pw[(1 * 8 + tt) * 512 + lane * 8], acc1[tt], 0, 0, 0);
#pragma unroll
        for (int tt = 0; tt < 8; ++tt)
            acc1[tt] = __builtin_amdgcn_mfma_f32_16x16x32_f16(a2, *(const half8*)&s_pw[(2 * 8 + tt) * 512 + lane * 8], acc1[tt], 0, 0, 0);

        // epilogue: u = relu(acc1) -> f16 packed u32 writes (BN folded into W2/b2p)
#pragma unroll
        for (int tt = 0; tt < 8; ++tt) {
#pragma unroll
            for (int r = 0; r < 4; ++r) {
                float v = fmaxf(acc1[tt][r], 0.f);
                float vo = __shfl_xor(v, 1);
                if (!(m & 1))
                    *(unsigned*)&h1[(4 * g + r) * H1_STRIDE + 16 * tt + m] = pkrtz(v, vo);
            }
        }
        asm volatile("s_waitcnt lgkmcnt(0)" ::: "memory");
        __builtin_amdgcn_sched_barrier(0);

        // ---- layer 2: [16,128] x [128,64] (W2 pre-scaled by BN gamma)
        f32x4 acc2[4] = {};
#pragma unroll
        for (int c = 0; c < 4; ++c) {
            half8 a = *(half8*)&h1[m * H1_STRIDE + 32 * c + 8 * g];
#pragma unroll
            for (int tt = 0; tt < 4; ++tt)
                acc2[tt] = __builtin_amdgcn_mfma_f32_16x16x32_f16(a, w2r[c * 4 + tt], acc2[tt], 0, 0, 0);
        }
        // ---- layer 3: relu(+b2p) dot w3, 16-lane reduce, sigmoid
        float s[4];
#pragma unroll
        for (int r = 0; r < 4; ++r) {
            float acc = 0.f;
#pragma unroll
            for (int tt = 0; tt < 4; ++tt) {
                float v = fmaxf(acc2[tt][r] + b2t[tt], 0.f);
                acc = fmaf(v, w3t[tt], acc);
            }
            acc += __shfl_xor(acc, 1);
            acc += __shfl_xor(acc, 2);
            acc += __shfl_xor(acc, 4);
            acc += __shfl_xor(acc, 8);
            s[r] = acc;
        }
        if (m == 0) {
            int eb = e0 + 4 * g;
            if (eb + 3 < E) {
                float4 o;
                o.x = 1.f / (1.f + expf(-(s[0] + b3)));
                o.y = 1.f / (1.f + expf(-(s[1] + b3)));
                o.z = 1.f / (1.f + expf(-(s[2] + b3)));
                o.w = 1.f / (1.f + expf(-(s[3] + b3)));
                *(float4*)(out + eb) = o;
            } else {
#pragma unroll
                for (int r = 0; r < 4; ++r)
                    if (eb + r < E) out[eb + r] = 1.f / (1.f + expf(-(s[r] + b3)));
            }
        }
        tile = nxt;
    }
}

// =====================================================================================
extern "C" void kernel_launch(void* const* d_in, const int* in_sizes, int n_in,
                              void* d_out, int out_size, void* d_ws, size_t ws_size,
                              hipStream_t stream)
{
    const float* x    = (const float*)d_in[0];
    const float* ea   = (const float*)d_in[1];
    const float* W0   = (const float*)d_in[2];
    const float* We0  = (const float*)d_in[3];
    const float* as0  = (const float*)d_in[4];
    const float* ad0  = (const float*)d_in[5];
    const float* ae0  = (const float*)d_in[6];
    const float* b0   = (const float*)d_in[7];
    const float* bn0g = (const float*)d_in[8];
    const float* bn0b = (const float*)d_in[9];
    const float* W1   = (const float*)d_in[10];
    const float* We1  = (const float*)d_in[11];
    const float* as1  = (const float*)d_in[12];
    const float* ad1  = (const float*)d_in[13];
    const float* ae1  = (const float*)d_in[14];
    const float* b1   = (const float*)d_in[15];
    const float* ndW1 = (const float*)d_in[16];
    const float* ndb1 = (const float*)d_in[17];
    const float* ndg  = (const float*)d_in[18];
    const float* ndbb = (const float*)d_in[19];
    const float* ndW2 = (const float*)d_in[20];
    const float* ndb2 = (const float*)d_in[21];
    const float* ndW3 = (const float*)d_in[22];
    const float* ndb3 = (const float*)d_in[23];
    const float* edW1 = (const float*)d_in[24];
    const float* edb1 = (const float*)d_in[25];
    const float* edg  = (const float*)d_in[26];
    const float* edbb = (const float*)d_in[27];
    const float* edW2 = (const float*)d_in[28];
    const float* edb2 = (const float*)d_in[29];
    const float* edW3 = (const float*)d_in[30];
    const float* edb3 = (const float*)d_in[31];
    const int*   eidx = (const int*)d_in[32];

    const int N = in_sizes[0] / 128;
    const int E = in_sizes[1] / 16;
    const int* srcA = eidx;
    const int* dstA = eidx + E;

    char* ws = (char*)d_ws;
    size_t o = 0;
    auto alloc = [&](size_t bytes) -> void* {
        void* p = ws + o;
        o = (o + bytes + 255) & ~(size_t)255;
        return p;
    };
    typedef unsigned short u16;
    u16*   xw0_16 = (u16*)alloc((size_t)N * 256 * 2);
    u16*   hbuf16 = (u16*)alloc((size_t)N * 256 * 2);
    u16*   xw1_16 = (u16*)alloc((size_t)N * 32 * 2);
    u16*   z16    = (u16*)alloc((size_t)N * 32 * 2);
    u16*   ea16   = (u16*)alloc((size_t)E * 16 * 2);
    float* a_s0   = (float*)alloc((size_t)N * 4 * 4);
    float* a_d0   = (float*)alloc((size_t)N * 4 * 4);
    float* a_e0a  = (float*)alloc((size_t)(E + N) * 4 * 4);
    float* a_e1a  = (float*)alloc((size_t)(E + N) * 4);
    float* a_s1   = (float*)alloc((size_t)N * 4);
    float* a_d1   = (float*)alloc((size_t)N * 4);
    int*   deg    = (int*)alloc((size_t)N * 4);
    int*   rowptr = (int*)alloc((size_t)(N + 1) * 4);
    int*   cur    = (int*)alloc((size_t)N * 4);
    int*   col    = (int*)alloc((size_t)(E + N) * 4);
    int*   bsum   = (int*)alloc(64 * 4);
    float* v0     = (float*)alloc(64 * 4);
    float* v1     = (float*)alloc(16 * 4);
    float* b2p    = (float*)alloc(64 * 4);
    u16*   pw     = (u16*)alloc((size_t)160 * 512 * 2);

    float* z_out    = (float*)d_out;
    float* node_out = z_out + (size_t)N * 32;
    float* edge_out = node_out + (size_t)N * 128;

    const int nb = (N + SCHUNK - 1) / SCHUNK;
    const int nrt = (N + 63) / 64;

    // weights / constants / CSR
    hipMemsetAsync(deg, 0, (size_t)N * 4, stream);
    k_pack_all<<<161, 512, 0, stream>>>(W0, W1, ndW1, ndW2, ndW3, edW1, edW2, edb1, edg,
                                        We0, ae0, We1, ae1, edbb, edb2, pw, v0, v1, b2p);
    k_edge_ae<<<(E + 255) / 256, 256, 0, stream>>>(ea, v0, v1, dstA, deg, a_e0a, a_e1a, ea16, E);
    k_scan1<<<nb, 1024, 0, stream>>>(deg, rowptr, bsum, N);
    k_scan3<<<(N + 255) / 256, 256, 0, stream>>>(bsum, deg, rowptr, cur, N);
    k_fill<<<(E + N + 255) / 256, 256, 0, stream>>>(dstA, cur, col, E, N);
    k_loop_mean<<<(N + 3) / 4, 256, 0, stream>>>(rowptr, col, ea16, v0, v1, a_e0a, a_e1a, N, E);

    // GAT layer 0 (fp32 x staged, col-split y=2, fused attention dots)
    k_gemm16<4, 8, 0, 1, 16, 1><<<dim3(nrt, 2), 256, 0, stream>>>(
        x, pw, xw0_16, N, nullptr, nullptr, nullptr, as0, ad0, a_s0, a_d0);
    k_gat0_agg<<<N, 64, 0, stream>>>(rowptr, col, srcA, a_s0, a_d0, a_e0a, xw0_16, b0, bn0g, bn0b,
                                     hbuf16, N, E);

    // GAT layer 1 (fused attention dots)
    k_gemm16<8, 2, 0, 0, 2, 2><<<dim3(nrt, 1), 256, 0, stream>>>(
        hbuf16, pw + (size_t)64 * 512, xw1_16, N, nullptr, nullptr, nullptr,
        as1, ad1, a_s1, a_d1);
    k_gat1_agg<<<N, 64, 0, stream>>>(rowptr, col, srcA, a_s1, a_d1, a_e1a, xw1_16, b1,
                                     z_out, z16, N, E);

    // fused node decoder (3 layers, one launch)
    k_node_dec<<<512, 256, 0, stream>>>(z16, pw + (size_t)80 * 512,
                                        ndb1, ndg, ndbb, ndb2, ndb3, node_out, N);

    // edge decoder (proven config: 256 thr, 3 blocks/CU, 768 blocks)
    k_edge_dec_mfma<<<768, 256, 0, stream>>>(z16, ea16, srcA, dstA, pw + (size_t)120 * 512,
                                             b2p, edW3, edb3, edge_out, E);
}

// Round 13
// 399.820 us; speedup vs baseline: 1.1116x; 1.0139x over previous
//
#include <hip/hip_runtime.h>
#include <math.h>

#define BN_K 0.9999950000374997f  // 1/sqrt(1+1e-5)

static __device__ __forceinline__ float lrelu02(float x) { return x > 0.f ? x : 0.2f * x; }

typedef _Float16 half8 __attribute__((ext_vector_type(8)));
typedef __fp16 fp16x2 __attribute__((ext_vector_type(2)));
typedef float f32x4 __attribute__((ext_vector_type(4)));

static __device__ __forceinline__ unsigned short f2h(float x)
{
    union { _Float16 h; unsigned short u; } q;
    q.h = (_Float16)x;
    return q.u;
}
static __device__ __forceinline__ float h2f(unsigned short u)
{
    union { unsigned short u; _Float16 h; } q;
    q.u = u;
    return (float)q.h;
}
static __device__ __forceinline__ unsigned pkrtz(float a, float b)
{
    union { fp16x2 h; unsigned u; } q;
    q.h = __builtin_amdgcn_cvt_pkrtz(a, b);
    return q.u;
}

// ---------------- CSR helpers ----------------
#define SCHUNK 4096
__global__ __launch_bounds__(1024) void k_scan1(const int* __restrict__ deg,
                                                int* __restrict__ rowptr,
                                                int* __restrict__ bsum, int n)
{
    __shared__ int sbuf[1024];
    int b = blockIdx.x, t = threadIdx.x;
    int i0 = b * SCHUNK + t * 4;
    int v[4];
#pragma unroll
    for (int j = 0; j < 4; ++j) v[j] = (i0 + j < n) ? deg[i0 + j] + 1 : 0;
    int s = v[0] + v[1] + v[2] + v[3];
    sbuf[t] = s;
    __syncthreads();
    for (int d = 1; d < 1024; d <<= 1) {
        int tmp = (t >= d) ? sbuf[t - d] : 0;
        __syncthreads();
        sbuf[t] += tmp;
        __syncthreads();
    }
    int run = sbuf[t] - s;
#pragma unroll
    for (int j = 0; j < 4; ++j) {
        run += v[j];
        if (i0 + j < n) rowptr[i0 + j + 1] = run;  // chunk-local inclusive
    }
    if (t == 1023) bsum[b] = sbuf[1023];
    if (b == 0 && t == 0) rowptr[0] = 0;
}

__global__ void k_scan3(const int* __restrict__ bsum, const int* __restrict__ deg,
                        int* __restrict__ rowptr, int* __restrict__ cur, int n)
{
    int i = blockIdx.x * blockDim.x + threadIdx.x;
    if (i >= n) return;
    int chunk = i / SCHUNK;
    int off = 0;
    for (int b = 0; b < chunk; ++b) off += bsum[b];
    int r = rowptr[i + 1] + off;
    rowptr[i + 1] = r;
    cur[i] = r - (deg[i] + 1);
}

__global__ void k_fill(const int* __restrict__ dst, int* __restrict__ cur,
                       int* __restrict__ col, int E, int N)
{
    int t = blockIdx.x * blockDim.x + threadIdx.x;
    if (t >= E + N) return;
    int d = (t < E) ? dst[t] : (t - E);
    int slot = atomicAdd(&cur[d], 1);
    col[slot] = t;  // eid: t<E original edge; t=E+i self-loop of node i
}

// ------- self-loop scatter-mean (from ea16) + fused self-loop attention-edge dots -------
__global__ __launch_bounds__(256) void k_loop_mean(
    const int* __restrict__ rowptr, const int* __restrict__ col,
    const unsigned short* __restrict__ ea16,
    const float* __restrict__ v0, const float* __restrict__ v1,
    float* __restrict__ a_e0, float* __restrict__ a_e1, int N, int E)
{
    int wv = threadIdx.x >> 6, lane = threadIdx.x & 63;
    int i = blockIdx.x * 4 + wv;
    if (i >= N) return;
    int beg = rowptr[i], end = rowptr[i + 1];
    int q = lane >> 4, k = lane & 15;
    float sum = 0.f;
    for (int p = beg + q; p < end; p += 4) {
        int eid = col[p];
        if (eid < E) sum += h2f(ea16[(size_t)eid * 16 + k]);
    }
    sum += __shfl_xor(sum, 16);
    sum += __shfl_xor(sum, 32);
    int cnt = end - beg - 1;  // exactly one self-loop per node
    float mean = sum / (float)max(cnt, 1);
    float p0 = mean * v0[q * 16 + k];
    float p1 = mean * v1[k];
#pragma unroll
    for (int mm = 1; mm < 16; mm <<= 1) { p0 += __shfl_xor(p0, mm); p1 += __shfl_xor(p1, mm); }
    if (k == 0) a_e0[(size_t)(E + i) * 4 + q] = p0;
    if (lane == 0) a_e1[E + i] = p1;
}

// ---- per-edge attention-edge terms + ea16 emit + fused deg count (original edges) ----
__global__ void k_edge_ae(const float* __restrict__ ea,
                          const float* __restrict__ v0, const float* __restrict__ v1,
                          const int* __restrict__ dstA, int* __restrict__ deg,
                          float* __restrict__ a_e0, float* __restrict__ a_e1,
                          unsigned short* __restrict__ ea16, int E)
{
    int idx = blockIdx.x * blockDim.x + threadIdx.x;
    if (idx >= E) return;
    atomicAdd(&deg[dstA[idx]], 1);
    const float* row = ea + (size_t)idx * 16;
    float r[16];
#pragma unroll
    for (int k = 0; k < 16; ++k) r[k] = row[k];
#pragma unroll
    for (int h = 0; h < 4; ++h) {
        float s = 0.f;
#pragma unroll
        for (int k = 0; k < 16; ++k) s = fmaf(r[k], v0[h * 16 + k], s);
        a_e0[(size_t)idx * 4 + h] = s;
    }
    float s1 = 0.f;
#pragma unroll
    for (int k = 0; k < 16; ++k) s1 = fmaf(r[k], v1[k], s1);
    a_e1[idx] = s1;
#pragma unroll
    for (int k = 0; k < 16; k += 4) {
        ushort4 o;
        o.x = f2h(r[k]); o.y = f2h(r[k + 1]); o.z = f2h(r[k + 2]); o.w = f2h(r[k + 3]);
        *(ushort4*)(ea16 + (size_t)idx * 16 + k) = o;
    }
}

// ---------------- pack ALL weights into f16 MFMA fragments (+ block 160 = tiny precompute) ---
// sigma(g,i)=8g+i; element (frag f, lane l, i) = W[k=32c+8g+i][n=16t+m], 0 if k>=K.
// frag ranges: [0,64) W0(128,256) c*16+t | [64,80) W1(256,32) c*2+t | [80,88) ndW1(32,128) t
// [88,104) ndW2(128,64) c*4+t | [104,120) ndW3(64,128) c*8+t
// [120,144) edW1(80,128) + bias row at k=80 | [144,160) edW2(128,64) rows scaled by g1*BN_K
__global__ __launch_bounds__(512) void k_pack_all(
    const float* __restrict__ W0, const float* __restrict__ W1,
    const float* __restrict__ nd1, const float* __restrict__ nd2, const float* __restrict__ nd3,
    const float* __restrict__ ed1, const float* __restrict__ ed2,
    const float* __restrict__ edb1, const float* __restrict__ edg,
    const float* __restrict__ We0, const float* __restrict__ ae0,
    const float* __restrict__ We1, const float* __restrict__ ae1,
    const float* __restrict__ edbb, const float* __restrict__ edb2,
    unsigned short* __restrict__ pw,
    float* __restrict__ v0, float* __restrict__ v1, float* __restrict__ b2p)
{
    int f = blockIdx.x, t = threadIdx.x;
    if (f == 160) {  // tiny precompute: v0, v1, b2p
        if (t < 64) {
            int h = t >> 4, k = t & 15;
            float s = 0.f;
            for (int c = 0; c < 64; ++c) s += We0[k * 256 + h * 64 + c] * ae0[h * 64 + c];
            v0[h * 16 + k] = s;
        } else if (t < 80) {
            int k = t - 64;
            float s = 0.f;
            for (int c = 0; c < 32; ++c) s += We1[k * 32 + c] * ae1[c];
            v1[k] = s;
        } else if (t < 144) {
            int n = t - 80;
            float s = 0.f;
            for (int k = 0; k < 128; ++k) s += edbb[k] * ed2[k * 64 + n];
            b2p[n] = edb2[n] + s;
        }
        return;
    }
    int l = t >> 3, i = t & 7, g = l >> 4, m = l & 15;
    float v;
    if (f < 64) {
        int q = f; int k = 32 * (q >> 4) + 8 * g + i, n = 16 * (q & 15) + m;
        v = W0[(size_t)k * 256 + n];
    } else if (f < 80) {
        int q = f - 64; int k = 32 * (q >> 1) + 8 * g + i, n = 16 * (q & 1) + m;
        v = W1[(size_t)k * 32 + n];
    } else if (f < 88) {
        int q = f - 80; int k = 8 * g + i, n = 16 * q + m;
        v = nd1[(size_t)k * 128 + n];
    } else if (f < 104) {
        int q = f - 88; int k = 32 * (q >> 2) + 8 * g + i, n = 16 * (q & 3) + m;
        v = nd2[(size_t)k * 64 + n];
    } else if (f < 120) {
        int q = f - 104; int k = 32 * (q >> 3) + 8 * g + i, n = 16 * (q & 7) + m;
        v = nd3[(size_t)k * 128 + n];
    } else if (f < 144) {
        int q = f - 120; int k = 32 * (q >> 3) + 8 * g + i, n = 16 * (q & 7) + m;
        v = (k < 80) ? ed1[(size_t)k * 128 + n] : (k == 80 ? edb1[n] : 0.f);
    } else {
        int q = f - 144; int k = 32 * (q >> 2) + 8 * g + i, n = 16 * (q & 3) + m;
        v = ed2[(size_t)k * 64 + n] * (edg[k] * BN_K);
    }
    pw[(size_t)f * 512 + t] = f2h(v);
}

// ---------------- generic f16 MFMA GEMM with epilogue (+fused attention dots) ----------------
// MODE 0: raw -> f16. DOTS: 1 = 4-head a_s/a_d dots (NT=8, grid.y=2), 2 = single-head (NT=2).
template <int KC, int NT, int MODE, int AF32, int NTOT, int DOTS>
__global__ __launch_bounds__(256) void k_gemm16(
    const void* __restrict__ Ain, const unsigned short* __restrict__ pwB,
    void* __restrict__ outp, int M,
    const float* __restrict__ bias, const float* __restrict__ g_,
    const float* __restrict__ bb_,
    const float* __restrict__ attS, const float* __restrict__ attD,
    float* __restrict__ a_sO, float* __restrict__ a_dO)
{
    constexpr int K = KC * 32;
    constexpr int LDA = K + 8;
    __shared__ unsigned short s_pw[KC * NT * 512];
    __shared__ unsigned short s_a[64 * LDA];
    __shared__ float s_c[3 * NT * 16];

    int t = threadIdx.x;
    int ttoff = blockIdx.y * NT;
    for (int idx = t; idx < KC * NT * 64; idx += 256) {
        int f = idx >> 6, e8 = idx & 63;
        int c = f / NT, tt = f - c * NT;
        *(half8*)&s_pw[(size_t)idx * 8] =
            *(const half8*)&pwB[(((size_t)(c * NTOT + ttoff + tt)) * 64 + e8) * 8];
    }
    if (MODE) {
        for (int c = t; c < NT * 16; c += 256) {
            s_c[c] = bias[ttoff * 16 + c];
            if (MODE == 2) {
                s_c[NT * 16 + c] = g_[ttoff * 16 + c] * BN_K;
                s_c[2 * NT * 16 + c] = bb_[ttoff * 16 + c];
            }
        }
    }
    int wv = t >> 6, lane = t & 63, gq = lane >> 4, m = lane & 15;

    float asv[NT], adv[NT];
    if (DOTS) {
#pragma unroll
        for (int tt = 0; tt < NT; ++tt) {
            asv[tt] = attS[ttoff * 16 + 16 * tt + m];
            adv[tt] = attD[ttoff * 16 + 16 * tt + m];
        }
    }

    int nrt = (M + 63) >> 6;
    for (int rt = blockIdx.x; rt < nrt; rt += gridDim.x) {
        int r0 = rt << 6;
        __syncthreads();
        for (int idx = t; idx < 64 * (K / 8); idx += 256) {
            int row = idx / (K / 8), cb = idx % (K / 8);
            half8 v = {};
            if (r0 + row < M) {
                if (AF32) {
                    const float* Af = (const float*)Ain + (size_t)(r0 + row) * K + cb * 8;
                    float4 u0 = *(const float4*)Af;
                    float4 u1 = *(const float4*)(Af + 4);
                    union { half8 h; unsigned u[4]; } q;
                    q.u[0] = pkrtz(u0.x, u0.y); q.u[1] = pkrtz(u0.z, u0.w);
                    q.u[2] = pkrtz(u1.x, u1.y); q.u[3] = pkrtz(u1.z, u1.w);
                    v = q.h;
                } else {
                    v = *(const half8*)&((const unsigned short*)Ain)[(size_t)(r0 + row) * K + cb * 8];
                }
            }
            *(half8*)&s_a[row * LDA + cb * 8] = v;
        }
        __syncthreads();
        f32x4 acc[NT] = {};
#pragma unroll
        for (int c = 0; c < KC; ++c) {
            half8 a = *(half8*)&s_a[(wv * 16 + m) * LDA + 32 * c + 8 * gq];
#pragma unroll
            for (int tt = 0; tt < NT; ++tt) {
                half8 b = *(const half8*)&s_pw[(c * NT + tt) * 512 + lane * 8];
                acc[tt] = __builtin_amdgcn_mfma_f32_16x16x32_f16(a, b, acc[tt], 0, 0, 0);
            }
        }
#pragma unroll
        for (int tt = 0; tt < NT; ++tt) {
            int col = 16 * tt + m;
            int ocol = ttoff * 16 + col;
            float cb = MODE ? s_c[col] : 0.f;
#pragma unroll
            for (int r = 0; r < 4; ++r) {
                int row = r0 + wv * 16 + 4 * gq + r;
                float v = acc[tt][r] + cb;
                if (MODE == 1) v = fmaxf(v, 0.f);
                if (MODE == 2) v = fmaxf(v, 0.f) * s_c[NT * 16 + col] + s_c[2 * NT * 16 + col];
                if (MODE == 3) {
                    if (row < M) ((float*)outp)[(size_t)row * (NTOT * 16) + ocol] = v;
                } else {
                    float o = __shfl_xor(v, 1);
                    if (!(m & 1) && row < M)
                        *(unsigned*)&((unsigned short*)outp)[(size_t)row * (NTOT * 16) + ocol] =
                            pkrtz(v, o);
                }
            }
        }
        if (DOTS == 1) {
#pragma unroll
            for (int r = 0; r < 4; ++r) {
                float psA = 0.f, pdA = 0.f, psB = 0.f, pdB = 0.f;
#pragma unroll
                for (int tt = 0; tt < NT && tt < 4; ++tt) {
                    psA = fmaf(acc[tt][r], asv[tt], psA);
                    pdA = fmaf(acc[tt][r], adv[tt], pdA);
                }
#pragma unroll
                for (int tt = 4; tt < NT; ++tt) {
                    psB = fmaf(acc[tt][r], asv[tt], psB);
                    pdB = fmaf(acc[tt][r], adv[tt], pdB);
                }
#pragma unroll
                for (int mm = 1; mm < 16; mm <<= 1) {
                    psA += __shfl_xor(psA, mm); pdA += __shfl_xor(pdA, mm);
                    psB += __shfl_xor(psB, mm); pdB += __shfl_xor(pdB, mm);
                }
                int row = r0 + wv * 16 + 4 * gq + r;
                if (m == 0 && row < M) {
                    int hA = 2 * blockIdx.y;
                    a_sO[(size_t)row * 4 + hA] = psA; a_sO[(size_t)row * 4 + hA + 1] = psB;
                    a_dO[(size_t)row * 4 + hA] = pdA; a_dO[(size_t)row * 4 + hA + 1] = pdB;
                }
            }
        } else if (DOTS == 2) {
#pragma unroll
            for (int r = 0; r < 4; ++r) {
                float ps = 0.f, pd = 0.f;
#pragma unroll
                for (int tt = 0; tt < NT; ++tt) {
                    ps = fmaf(acc[tt][r], asv[tt], ps);
                    pd = fmaf(acc[tt][r], adv[tt], pd);
                }
#pragma unroll
                for (int mm = 1; mm < 16; mm <<= 1) {
                    ps += __shfl_xor(ps, mm); pd += __shfl_xor(pd, mm);
                }
                int row = r0 + wv * 16 + 4 * gq + r;
                if (m == 0 && row < M) { a_sO[row] = ps; a_dO[row] = pd; }
            }
        }
    }
}

// ---------------- GAT layer 0 aggregation: wave per node, src cached, 4x unrolled gather -----
__global__ __launch_bounds__(64) void k_gat0_agg(
    const int* __restrict__ rowptr, const int* __restrict__ col, const int* __restrict__ srcA,
    const float* __restrict__ a_s, const float* __restrict__ a_d, const float* __restrict__ a_e,
    const unsigned short* __restrict__ xw16, const float* __restrict__ b0,
    const float* __restrict__ bng, const float* __restrict__ bnb,
    unsigned short* __restrict__ hout16, int N, int E)
{
    int i = blockIdx.x;
    int lane = threadIdx.x;
    int beg = rowptr[i], end = rowptr[i + 1];
    float ad[4];
#pragma unroll
    for (int h = 0; h < 4; ++h) ad[h] = a_d[(size_t)i * 4 + h];

    float al[4] = {-1e30f, -1e30f, -1e30f, -1e30f};
    int sl0 = i;
    int p0 = beg + lane;
    if (p0 < end) {
        int eid = col[p0];
        sl0 = (eid < E) ? srcA[eid] : i;
        float4 as4 = *(const float4*)(a_s + (size_t)sl0 * 4);
        float4 ae4 = *(const float4*)(a_e + (size_t)eid * 4);
        al[0] = lrelu02(as4.x + ad[0] + ae4.x);
        al[1] = lrelu02(as4.y + ad[1] + ae4.y);
        al[2] = lrelu02(as4.z + ad[2] + ae4.z);
        al[3] = lrelu02(as4.w + ad[3] + ae4.w);
    }
    float mx[4] = {al[0], al[1], al[2], al[3]};
    for (int p = p0 + 64; p < end; p += 64) {
        int eid = col[p];
        int s = (eid < E) ? srcA[eid] : i;
        float4 as4 = *(const float4*)(a_s + (size_t)s * 4);
        float4 ae4 = *(const float4*)(a_e + (size_t)eid * 4);
        mx[0] = fmaxf(mx[0], lrelu02(as4.x + ad[0] + ae4.x));
        mx[1] = fmaxf(mx[1], lrelu02(as4.y + ad[1] + ae4.y));
        mx[2] = fmaxf(mx[2], lrelu02(as4.z + ad[2] + ae4.z));
        mx[3] = fmaxf(mx[3], lrelu02(as4.w + ad[3] + ae4.w));
    }
#pragma unroll
    for (int h = 0; h < 4; ++h)
#pragma unroll
        for (int m = 1; m < 64; m <<= 1) mx[h] = fmaxf(mx[h], __shfl_xor(mx[h], m));

    __shared__ float wls[256];
    __shared__ int s_src[64];
    int hl = lane >> 4;
    float accx = 0.f, accy = 0.f, accz = 0.f, accw = 0.f;
    float s0 = 0.f, s1 = 0.f, s2 = 0.f, s3 = 0.f;
    for (int base = beg; base < end; base += 64) {
        int p = base + lane;
        int cnt = min(64, end - base);
        if (p < end) {
            float aa0, aa1, aa2, aa3;
            int s;
            if (base == beg) {
                s = sl0;
                aa0 = al[0]; aa1 = al[1]; aa2 = al[2]; aa3 = al[3];
            } else {
                int eid = col[p];
                s = (eid < E) ? srcA[eid] : i;
                float4 as4 = *(const float4*)(a_s + (size_t)s * 4);
                float4 ae4 = *(const float4*)(a_e + (size_t)eid * 4);
                aa0 = lrelu02(as4.x + ad[0] + ae4.x);
                aa1 = lrelu02(as4.y + ad[1] + ae4.y);
                aa2 = lrelu02(as4.z + ad[2] + ae4.z);
                aa3 = lrelu02(as4.w + ad[3] + ae4.w);
            }
            float w0 = expf(aa0 - mx[0]);
            float w1 = expf(aa1 - mx[1]);
            float w2 = expf(aa2 - mx[2]);
            float w3 = expf(aa3 - mx[3]);
            s0 += w0; s1 += w1; s2 += w2; s3 += w3;
            wls[lane * 4 + 0] = w0; wls[lane * 4 + 1] = w1;
            wls[lane * 4 + 2] = w2; wls[lane * 4 + 3] = w3;
            s_src[lane] = s;
        }
        __syncthreads();
        int q = 0;
        for (; q + 3 < cnt; q += 4) {
            int ss0 = s_src[q], ss1 = s_src[q + 1], ss2 = s_src[q + 2], ss3 = s_src[q + 3];
            ushort4 x0 = *(const ushort4*)(xw16 + (size_t)ss0 * 256 + lane * 4);
            ushort4 x1 = *(const ushort4*)(xw16 + (size_t)ss1 * 256 + lane * 4);
            ushort4 x2 = *(const ushort4*)(xw16 + (size_t)ss2 * 256 + lane * 4);
            ushort4 x3 = *(const ushort4*)(xw16 + (size_t)ss3 * 256 + lane * 4);
            float w0 = wls[q * 4 + hl], w1 = wls[(q + 1) * 4 + hl];
            float w2 = wls[(q + 2) * 4 + hl], w3 = wls[(q + 3) * 4 + hl];
            accx = fmaf(w0, h2f(x0.x), accx); accy = fmaf(w0, h2f(x0.y), accy);
            accz = fmaf(w0, h2f(x0.z), accz); accw = fmaf(w0, h2f(x0.w), accw);
            accx = fmaf(w1, h2f(x1.x), accx); accy = fmaf(w1, h2f(x1.y), accy);
            accz = fmaf(w1, h2f(x1.z), accz); accw = fmaf(w1, h2f(x1.w), accw);
            accx = fmaf(w2, h2f(x2.x), accx); accy = fmaf(w2, h2f(x2.y), accy);
            accz = fmaf(w2, h2f(x2.z), accz); accw = fmaf(w2, h2f(x2.w), accw);
            accx = fmaf(w3, h2f(x3.x), accx); accy = fmaf(w3, h2f(x3.y), accy);
            accz = fmaf(w3, h2f(x3.z), accz); accw = fmaf(w3, h2f(x3.w), accw);
        }
        for (; q < cnt; ++q) {
            int ss = s_src[q];
            float w = wls[q * 4 + hl];
            ushort4 xv = *(const ushort4*)(xw16 + (size_t)ss * 256 + lane * 4);
            accx = fmaf(w, h2f(xv.x), accx);
            accy = fmaf(w, h2f(xv.y), accy);
            accz = fmaf(w, h2f(xv.z), accz);
            accw = fmaf(w, h2f(xv.w), accw);
        }
        __syncthreads();
    }
#pragma unroll
    for (int m = 1; m < 64; m <<= 1) {
        s0 += __shfl_xor(s0, m); s1 += __shfl_xor(s1, m);
        s2 += __shfl_xor(s2, m); s3 += __shfl_xor(s3, m);
    }
    float sden = ((hl == 0) ? s0 : (hl == 1) ? s1 : (hl == 2) ? s2 : s3) + 1e-16f;

    int ch = lane * 4;
    float out[4] = {accx / sden, accy / sden, accz / sden, accw / sden};
    ushort4 ov;
    unsigned short* po = (unsigned short*)&ov;
#pragma unroll
    for (int j = 0; j < 4; ++j) {
        int c = ch + j;
        float v = out[j] + b0[c];
        v = v * (BN_K * bng[c]) + bnb[c];
        po[j] = f2h((v > 0.f) ? v : expm1f(v));
    }
    *(ushort4*)(hout16 + (size_t)i * 256 + ch) = ov;
}

// ------- GAT layer 1 aggregation v2: 4 edges/wave-step, ushort2 loads, subgroup reduce -------
__global__ __launch_bounds__(64) void k_gat1_agg(
    const int* __restrict__ rowptr, const int* __restrict__ col, const int* __restrict__ srcA,
    const float* __restrict__ a_s, const float* __restrict__ a_d, const float* __restrict__ a_e,
    const unsigned short* __restrict__ xw16, const float* __restrict__ b1,
    float* __restrict__ zout, unsigned short* __restrict__ z16, int N, int E)
{
    int i = blockIdx.x;
    int lane = threadIdx.x;
    int beg = rowptr[i], end = rowptr[i + 1];
    float ad = a_d[i];
    float al = -1e30f;
    int sl0 = i;
    int p0 = beg + lane;
    if (p0 < end) {
        int eid = col[p0];
        sl0 = (eid < E) ? srcA[eid] : i;
        al = lrelu02(a_s[sl0] + ad + a_e[eid]);
    }
    float mx = al;
    for (int p = p0 + 64; p < end; p += 64) {
        int eid = col[p];
        int s = (eid < E) ? srcA[eid] : i;
        mx = fmaxf(mx, lrelu02(a_s[s] + ad + a_e[eid]));
    }
#pragma unroll
    for (int m = 1; m < 64; m <<= 1) mx = fmaxf(mx, __shfl_xor(mx, m));

    __shared__ float wls[64];
    __shared__ int s_src[64];
    float accA = 0.f, accB = 0.f, ssum = 0.f;
    int sub = lane >> 4;          // edge sub-group 0..3
    int ch = (lane & 15) * 2;     // this lane's channel pair
    for (int base = beg; base < end; base += 64) {
        int p = base + lane;
        int cnt = min(64, end - base);
        if (p < end) {
            float aa;
            int s;
            if (base == beg) { s = sl0; aa = al; }
            else {
                int eid = col[p];
                s = (eid < E) ? srcA[eid] : i;
                aa = lrelu02(a_s[s] + ad + a_e[eid]);
            }
            float w = expf(aa - mx);
            ssum += w;
            wls[lane] = w;
            s_src[lane] = s;
        }
        __syncthreads();
        int q = sub;
        for (; q + 12 < cnt; q += 16) {
            int ss0 = s_src[q], ss1 = s_src[q + 4], ss2 = s_src[q + 8], ss3 = s_src[q + 12];
            float w0 = wls[q], w1 = wls[q + 4], w2 = wls[q + 8], w3 = wls[q + 12];
            ushort2 x0 = *(const ushort2*)(xw16 + (size_t)ss0 * 32 + ch);
            ushort2 x1 = *(const ushort2*)(xw16 + (size_t)ss1 * 32 + ch);
            ushort2 x2 = *(const ushort2*)(xw16 + (size_t)ss2 * 32 + ch);
            ushort2 x3 = *(const ushort2*)(xw16 + (size_t)ss3 * 32 + ch);
            accA = fmaf(w0, h2f(x0.x), accA); accB = fmaf(w0, h2f(x0.y), accB);
            accA = fmaf(w1, h2f(x1.x), accA); accB = fmaf(w1, h2f(x1.y), accB);
            accA = fmaf(w2, h2f(x2.x), accA); accB = fmaf(w2, h2f(x2.y), accB);
            accA = fmaf(w3, h2f(x3.x), accA); accB = fmaf(w3, h2f(x3.y), accB);
        }
        for (; q < cnt; q += 4) {
            int ss = s_src[q];
            float w = wls[q];
            ushort2 xv = *(const ushort2*)(xw16 + (size_t)ss * 32 + ch);
            accA = fmaf(w, h2f(xv.x), accA);
            accB = fmaf(w, h2f(xv.y), accB);
        }
        __syncthreads();
    }
#pragma unroll
    for (int m = 1; m < 64; m <<= 1) ssum += __shfl_xor(ssum, m);
    accA += __shfl_xor(accA, 16); accB += __shfl_xor(accB, 16);
    accA += __shfl_xor(accA, 32); accB += __shfl_xor(accB, 32);
    if (lane < 16) {
        float inv = 1.f / (ssum + 1e-16f);
        float vA = accA * inv + b1[ch];
        float vB = accB * inv + b1[ch + 1];
        *(float2*)(zout + (size_t)i * 32 + ch) = make_float2(vA, vB);
        *(unsigned*)(z16 + (size_t)i * 32 + ch) = pkrtz(vA, vB);
    }
}

// ------- fused node decoder: z16 -> BN(relu(@nd1)) -> relu(@nd2) -> @nd3 + b (fp32) -------
#define N1_STRIDE 136
#define H2_STRIDE 72

__global__ __launch_bounds__(256, 2) void k_node_dec(
    const unsigned short* __restrict__ z16, const unsigned short* __restrict__ pw,  // nd frags
    const float* __restrict__ b1, const float* __restrict__ g1, const float* __restrict__ bb1,
    const float* __restrict__ b2, const float* __restrict__ b3,
    float* __restrict__ out, int N)
{
    __shared__ unsigned short s_pw[40 * 512];          // nd1[0,8) nd2[8,24) nd3[24,40)
    __shared__ unsigned short s_z[64 * 40];
    __shared__ unsigned short s_n1[4][16 * N1_STRIDE];
    __shared__ unsigned short s_h2[4][16 * H2_STRIDE];
    __shared__ float s_c[128 * 3 + 64 + 128];          // b1|g1k|bb1|b2|b3

    int t = threadIdx.x;
    for (int idx = t; idx < 2560; idx += 256)
        *(half8*)&s_pw[idx * 8] = *(const half8*)&pw[idx * 8];
    if (t < 128) {
        s_c[t] = b1[t];
        s_c[128 + t] = g1[t] * BN_K;
        s_c[256 + t] = bb1[t];
        s_c[448 + t] = b3[t];
    }
    if (t < 64) s_c[384 + t] = b2[t];
    __syncthreads();

    int wv = t >> 6, lane = t & 63;
    int g = lane >> 4, m = lane & 15;
    unsigned short* n1 = s_n1[wv];
    unsigned short* h2 = s_h2[wv];

    int nrt = (N + 63) >> 6;
    for (int rt = blockIdx.x; rt < nrt; rt += gridDim.x) {
        int r0 = rt << 6;
        __syncthreads();
        {   // stage z tile: 64 rows x 32 f16; 256 threads x 1 half8
            int row = t >> 2, cb = t & 3;
            half8 v = {};
            if (r0 + row < N) v = *(const half8*)&z16[(size_t)(r0 + row) * 32 + cb * 8];
            *(half8*)&s_z[row * 40 + cb * 8] = v;
        }
        __syncthreads();

        // ---- L1: [16,32] x [32,128] -> n1 (BN(relu(+b1))), per-wave rows wv*16..+16
        f32x4 acc1[8] = {};
        {
            half8 a = *(half8*)&s_z[(wv * 16 + m) * 40 + 8 * g];
#pragma unroll
            for (int tt = 0; tt < 8; ++tt)
                acc1[tt] = __builtin_amdgcn_mfma_f32_16x16x32_f16(
                    a, *(const half8*)&s_pw[tt * 512 + lane * 8], acc1[tt], 0, 0, 0);
        }
#pragma unroll
        for (int tt = 0; tt < 8; ++tt) {
            int col = 16 * tt + m;
            float cb = s_c[col], cg = s_c[128 + col], cbb = s_c[256 + col];
#pragma unroll
            for (int r = 0; r < 4; ++r) {
                float v = fmaxf(acc1[tt][r] + cb, 0.f) * cg + cbb;
                float vo = __shfl_xor(v, 1);
                if (!(m & 1))
                    *(unsigned*)&n1[(4 * g + r) * N1_STRIDE + 16 * tt + m] = pkrtz(v, vo);
            }
        }
        asm volatile("s_waitcnt lgkmcnt(0)" ::: "memory");
        __builtin_amdgcn_sched_barrier(0);

        // ---- L2: [16,128] x [128,64] -> h2 (relu(+b2))
        f32x4 acc2[4] = {};
#pragma unroll
        for (int c = 0; c < 4; ++c) {
            half8 a = *(half8*)&n1[m * N1_STRIDE + 32 * c + 8 * g];
#pragma unroll
            for (int tt = 0; tt < 4; ++tt)
                acc2[tt] = __builtin_amdgcn_mfma_f32_16x16x32_f16(
                    a, *(const half8*)&s_pw[(8 + c * 4 + tt) * 512 + lane * 8], acc2[tt], 0, 0, 0);
        }
#pragma unroll
        for (int tt = 0; tt < 4; ++tt) {
            int col = 16 * tt + m;
            float cb = s_c[384 + col];
#pragma unroll
            for (int r = 0; r < 4; ++r) {
                float v = fmaxf(acc2[tt][r] + cb, 0.f);
                float vo = __shfl_xor(v, 1);
                if (!(m & 1))
                    *(unsigned*)&h2[(4 * g + r) * H2_STRIDE + 16 * tt + m] = pkrtz(v, vo);
            }
        }
        asm volatile("s_waitcnt lgkmcnt(0)" ::: "memory");
        __builtin_amdgcn_sched_barrier(0);

        // ---- L3: [16,64] x [64,128] -> out fp32 (+b3)
        f32x4 acc3[8] = {};
#pragma unroll
        for (int c = 0; c < 2; ++c) {
            half8 a = *(half8*)&h2[m * H2_STRIDE + 32 * c + 8 * g];
#pragma unroll
            for (int tt = 0; tt < 8; ++tt)
                acc3[tt] = __builtin_amdgcn_mfma_f32_16x16x32_f16(
                    a, *(const half8*)&s_pw[(24 + c * 8 + tt) * 512 + lane * 8], acc3[tt], 0, 0, 0);
        }
#pragma unroll
        for (int tt = 0; tt < 8; ++tt) {
            int col = 16 * tt + m;
            float cb = s_c[448 + col];
#pragma unroll
            for (int r = 0; r < 4; ++r) {
                int row = r0 + wv * 16 + 4 * g + r;
                if (row < N) out[(size_t)row * 128 + col] = acc3[tt][r] + cb;
            }
        }
    }
}

// ---- MFMA edge decoder v5: 2-deep pipeline (indices t+2, gathers t+1), setprio on MFMA ----
#define H1_STRIDE 136

__global__ __launch_bounds__(256, 3) void k_edge_dec_mfma(
    const unsigned short* __restrict__ z16, const unsigned short* __restrict__ ea16,
    const int* __restrict__ srcA, const int* __restrict__ dstA,
    const unsigned short* __restrict__ pw,  // [0,24)=edW1+b1row, [24,40)=edW2*gscale
    const float* __restrict__ b2p, const float* __restrict__ w3,
    const float* __restrict__ b3v, float* __restrict__ out, int E)
{
    __shared__ unsigned short s_pw[24 * 512];
    __shared__ unsigned short s_h1[4][16 * H1_STRIDE];

    int t = threadIdx.x;
    for (int idx = t; idx < 1536; idx += 256)
        *(half8*)&s_pw[idx * 8] = *(const half8*)&pw[idx * 8];
    __syncthreads();

    int wv = t >> 6, lane = t & 63;
    int g = lane >> 4, m = lane & 15;
    unsigned short* h1 = s_h1[wv];

    half8 w2r[16];
#pragma unroll
    for (int q = 0; q < 16; ++q)
        w2r[q] = *(const half8*)&pw[(size_t)(24 + q) * 512 + lane * 8];

    float w3t[4], b2t[4];
#pragma unroll
    for (int q = 0; q < 4; ++q) { w3t[q] = w3[16 * q + m]; b2t[q] = b2p[16 * q + m]; }
    float b3 = b3v[0];

    int ntiles = (E + 15) >> 4;
    int gw = blockIdx.x * 4 + wv;
    int nw = gridDim.x * 4;

    // prologue: indices + gathers for tile gw; indices for tile gw+nw
    half8 a0n = {}, a1n = {}, a2n = {};
    {
        int e = (gw << 4) + m;
        if (gw < ntiles && e < E) {
            int si = srcA[e], di = dstA[e];
            a0n = *(const half8*)&z16[(size_t)si * 32 + 8 * g];
            a1n = *(const half8*)&z16[(size_t)di * 32 + 8 * g];
            if (g < 2) a2n = *(const half8*)&ea16[(size_t)e * 16 + 8 * g];
        }
        if (g == 2) a2n[0] = (_Float16)1.f;  // k=80 constant -> b1 row of edW1
    }
    int sip = 0, dip = 0;
    {
        int nxt = gw + nw;
        int e = (nxt << 4) + m;
        if (nxt < ntiles && e < E) { sip = srcA[e]; dip = dstA[e]; }
    }

    for (int tile = gw; tile < ntiles; ) {
        half8 a0 = a0n, a1 = a1n, a2 = a2n;
        int e0 = tile << 4;
        int nxt = tile + nw;
        int nxt2 = tile + 2 * nw;

        // stage 1: gathers for tile nxt using pre-loaded indices (no load->gather chain)
        a0n = half8{}; a1n = half8{}; a2n = half8{};
        {
            int e = (nxt << 4) + m;
            if (nxt < ntiles && e < E) {
                a0n = *(const half8*)&z16[(size_t)sip * 32 + 8 * g];
                a1n = *(const half8*)&z16[(size_t)dip * 32 + 8 * g];
                if (g < 2) a2n = *(const half8*)&ea16[(size_t)e * 16 + 8 * g];
            }
            if (g == 2) a2n[0] = (_Float16)1.f;
        }
        // stage 2: indices for tile nxt2
        {
            int e = (nxt2 << 4) + m;
            if (nxt2 < ntiles && e < E) { sip = srcA[e]; dip = dstA[e]; }
        }

        // ---- layer 1: [16,96] x [96,128], bias baked in
        f32x4 acc1[8] = {};
        __builtin_amdgcn_s_setprio(1);
#pragma unroll
        for (int tt = 0; tt < 8; ++tt)
            acc1[tt] = __builtin_amdgcn_mfma_f32_16x16x32_f16(a0, *(const half8*)&s_pw[(0 * 8 + tt) * 512 + lane * 8], acc1[tt], 0, 0, 0);
#pragma unroll
        for (int tt = 0; tt < 8; ++tt)
            acc1[tt] = __builtin_amdgcn_mfma_f32_16x16x32_f16(a1, *(const half8*)&s_pw[(1 * 8 + tt) * 512 + lane * 8], acc1[tt], 0, 0, 0);
#pragma unroll
        for (int tt = 0; tt < 8; ++tt)
            acc1[tt] = __builtin_amdgcn_mfma_f32_16x16x32_f16(a2, *(const half8*)&s_pw[(2 * 8 + tt) * 512 + lane * 8], acc1[tt], 0, 0, 0);
        __builtin_amdgcn_s_setprio(0);

        // epilogue: u = relu(acc1) -> f16 packed u32 writes (BN folded into W2/b2p)
#pragma unroll
        for (int tt = 0; tt < 8; ++tt) {
#pragma unroll
            for (int r = 0; r < 4; ++r) {
                float v = fmaxf(acc1[tt][r], 0.f);
                float vo = __shfl_xor(v, 1);
                if (!(m & 1))
                    *(unsigned*)&h1[(4 * g + r) * H1_STRIDE + 16 * tt + m] = pkrtz(v, vo);
            }
        }
        asm volatile("s_waitcnt lgkmcnt(0)" ::: "memory");
        __builtin_amdgcn_sched_barrier(0);

        // ---- layer 2: [16,128] x [128,64] (W2 pre-scaled by BN gamma)
        f32x4 acc2[4] = {};
        __builtin_amdgcn_s_setprio(1);
#pragma unroll
        for (int c = 0; c < 4; ++c) {
            half8 a = *(half8*)&h1[m * H1_STRIDE + 32 * c + 8 * g];
#pragma unroll
            for (int tt = 0; tt < 4; ++tt)
                acc2[tt] = __builtin_amdgcn_mfma_f32_16x16x32_f16(a, w2r[c * 4 + tt], acc2[tt], 0, 0, 0);
        }
        __builtin_amdgcn_s_setprio(0);

        // ---- layer 3: relu(+b2p) dot w3, 16-lane reduce, sigmoid
        float s[4];
#pragma unroll
        for (int r = 0; r < 4; ++r) {
            float acc = 0.f;
#pragma unroll
            for (int tt = 0; tt < 4; ++tt) {
                float v = fmaxf(acc2[tt][r] + b2t[tt], 0.f);
                acc = fmaf(v, w3t[tt], acc);
            }
            acc += __shfl_xor(acc, 1);
            acc += __shfl_xor(acc, 2);
            acc += __shfl_xor(acc, 4);
            acc += __shfl_xor(acc, 8);
            s[r] = acc;
        }
        if (m == 0) {
            int eb = e0 + 4 * g;
            if (eb + 3 < E) {
                float4 o;
                o.x = 1.f / (1.f + expf(-(s[0] + b3)));
                o.y = 1.f / (1.f + expf(-(s[1] + b3)));
                o.z = 1.f / (1.f + expf(-(s[2] + b3)));
                o.w = 1.f / (1.f + expf(-(s[3] + b3)));
                *(float4*)(out + eb) = o;
            } else {
#pragma unroll
                for (int r = 0; r < 4; ++r)
                    if (eb + r < E) out[eb + r] = 1.f / (1.f + expf(-(s[r] + b3)));
            }
        }
        tile = nxt;
    }
}

// =====================================================================================
extern "C" void kernel_launch(void* const* d_in, const int* in_sizes, int n_in,
                              void* d_out, int out_size, void* d_ws, size_t ws_size,
                              hipStream_t stream)
{
    const float* x    = (const float*)d_in[0];
    const float* ea   = (const float*)d_in[1];
    const float* W0   = (const float*)d_in[2];
    const float* We0  = (const float*)d_in[3];
    const float* as0  = (const float*)d_in[4];
    const float* ad0  = (const float*)d_in[5];
    const float* ae0  = (const float*)d_in[6];
    const float* b0   = (const float*)d_in[7];
    const float* bn0g = (const float*)d_in[8];
    const float* bn0b = (const float*)d_in[9];
    const float* W1   = (const float*)d_in[10];
    const float* We1  = (const float*)d_in[11];
    const float* as1  = (const float*)d_in[12];
    const float* ad1  = (const float*)d_in[13];
    const float* ae1  = (const float*)d_in[14];
    const float* b1   = (const float*)d_in[15];
    const float* ndW1 = (const float*)d_in[16];
    const float* ndb1 = (const float*)d_in[17];
    const float* ndg  = (const float*)d_in[18];
    const float* ndbb = (const float*)d_in[19];
    const float* ndW2 = (const float*)d_in[20];
    const float* ndb2 = (const float*)d_in[21];
    const float* ndW3 = (const float*)d_in[22];
    const float* ndb3 = (const float*)d_in[23];
    const float* edW1 = (const float*)d_in[24];
    const float* edb1 = (const float*)d_in[25];
    const float* edg  = (const float*)d_in[26];
    const float* edbb = (const float*)d_in[27];
    const float* edW2 = (const float*)d_in[28];
    const float* edb2 = (const float*)d_in[29];
    const float* edW3 = (const float*)d_in[30];
    const float* edb3 = (const float*)d_in[31];
    const int*   eidx = (const int*)d_in[32];

    const int N = in_sizes[0] / 128;
    const int E = in_sizes[1] / 16;
    const int* srcA = eidx;
    const int* dstA = eidx + E;

    char* ws = (char*)d_ws;
    size_t o = 0;
    auto alloc = [&](size_t bytes) -> void* {
        void* p = ws + o;
        o = (o + bytes + 255) & ~(size_t)255;
        return p;
    };
    typedef unsigned short u16;
    u16*   xw0_16 = (u16*)alloc((size_t)N * 256 * 2);
    u16*   hbuf16 = (u16*)alloc((size_t)N * 256 * 2);
    u16*   xw1_16 = (u16*)alloc((size_t)N * 32 * 2);
    u16*   z16    = (u16*)alloc((size_t)N * 32 * 2);
    u16*   ea16   = (u16*)alloc((size_t)E * 16 * 2);
    float* a_s0   = (float*)alloc((size_t)N * 4 * 4);
    float* a_d0   = (float*)alloc((size_t)N * 4 * 4);
    float* a_e0a  = (float*)alloc((size_t)(E + N) * 4 * 4);
    float* a_e1a  = (float*)alloc((size_t)(E + N) * 4);
    float* a_s1   = (float*)alloc((size_t)N * 4);
    float* a_d1   = (float*)alloc((size_t)N * 4);
    int*   deg    = (int*)alloc((size_t)N * 4);
    int*   rowptr = (int*)alloc((size_t)(N + 1) * 4);
    int*   cur    = (int*)alloc((size_t)N * 4);
    int*   col    = (int*)alloc((size_t)(E + N) * 4);
    int*   bsum   = (int*)alloc(64 * 4);
    float* v0     = (float*)alloc(64 * 4);
    float* v1     = (float*)alloc(16 * 4);
    float* b2p    = (float*)alloc(64 * 4);
    u16*   pw     = (u16*)alloc((size_t)160 * 512 * 2);

    float* z_out    = (float*)d_out;
    float* node_out = z_out + (size_t)N * 32;
    float* edge_out = node_out + (size_t)N * 128;

    const int nb = (N + SCHUNK - 1) / SCHUNK;
    const int nrt = (N + 63) / 64;

    // weights / constants / CSR
    hipMemsetAsync(deg, 0, (size_t)N * 4, stream);
    k_pack_all<<<161, 512, 0, stream>>>(W0, W1, ndW1, ndW2, ndW3, edW1, edW2, edb1, edg,
                                        We0, ae0, We1, ae1, edbb, edb2, pw, v0, v1, b2p);
    k_edge_ae<<<(E + 255) / 256, 256, 0, stream>>>(ea, v0, v1, dstA, deg, a_e0a, a_e1a, ea16, E);
    k_scan1<<<nb, 1024, 0, stream>>>(deg, rowptr, bsum, N);
    k_scan3<<<(N + 255) / 256, 256, 0, stream>>>(bsum, deg, rowptr, cur, N);
    k_fill<<<(E + N + 255) / 256, 256, 0, stream>>>(dstA, cur, col, E, N);
    k_loop_mean<<<(N + 3) / 4, 256, 0, stream>>>(rowptr, col, ea16, v0, v1, a_e0a, a_e1a, N, E);

    // GAT layer 0 (fp32 x staged, col-split y=2, fused attention dots)
    k_gemm16<4, 8, 0, 1, 16, 1><<<dim3(nrt, 2), 256, 0, stream>>>(
        x, pw, xw0_16, N, nullptr, nullptr, nullptr, as0, ad0, a_s0, a_d0);
    k_gat0_agg<<<N, 64, 0, stream>>>(rowptr, col, srcA, a_s0, a_d0, a_e0a, xw0_16, b0, bn0g, bn0b,
                                     hbuf16, N, E);

    // GAT layer 1 (fused attention dots)
    k_gemm16<8, 2, 0, 0, 2, 2><<<dim3(nrt, 1), 256, 0, stream>>>(
        hbuf16, pw + (size_t)64 * 512, xw1_16, N, nullptr, nullptr, nullptr,
        as1, ad1, a_s1, a_d1);
    k_gat1_agg<<<N, 64, 0, stream>>>(rowptr, col, srcA, a_s1, a_d1, a_e1a, xw1_16, b1,
                                     z_out, z16, N, E);

    // fused node decoder (3 layers, one launch)
    k_node_dec<<<512, 256, 0, stream>>>(z16, pw + (size_t)80 * 512,
                                        ndb1, ndg, ndbb, ndb2, ndb3, node_out, N);

    // edge decoder (256 thr, 3 blocks/CU, 768 blocks; 2-deep pipeline)
    k_edge_dec_mfma<<<768, 256, 0, stream>>>(z16, ea16, srcA, dstA, pw + (size_t)120 * 512,
                                             b2p, edW3, edb3, edge_out, E);
}